// Round 7
// baseline (586.479 us; speedup 1.0000x reference)
//
#include <hip/hip_runtime.h>
#include <cstdint>
#include <cstddef>

#define N_ANCH 20000
#define N_CLS  80
#define MAXDET 300
#define NMS_T  512
#define ELEMS  40      // scores per thread (40 = 10 float4)
#define SORTN  1024    // NMS bitonic sort size (pow2)
#define KSEL   896     // target top-K per selection round
#define NB     1024    // coarse histogram buckets (564 used; pow2)
#define MSORT  1024    // merge sort size
#define BUCKET_BASE 0x3D4C  // float bits of ~0.05 >> 16

#define TP_T   320     // transpose threads
#define TILE_A 160     // anchors per transpose tile (20000 = 125 * 160)

__device__ __forceinline__ float box_area(float4 b) {
  return __fmul_rn(__fsub_rn(b.z, b.x), __fsub_rn(b.w, b.y));
}

// IOU, unfused IEEE ops, exactly the reference's association order.
// a = candidate (its area first in denom), b = picked/selected.
__device__ __forceinline__ bool iou_gt_half(float4 a, float aa, float4 b, float ab) {
  const float xx1 = fmaxf(a.x, b.x);
  const float yy1 = fmaxf(a.y, b.y);
  const float xx2 = fminf(a.z, b.z);
  const float yy2 = fminf(a.w, b.w);
  const float iw  = fmaxf(__fsub_rn(xx2, xx1), 0.0f);
  const float ih  = fmaxf(__fsub_rn(yy2, yy1), 0.0f);
  const float inter = __fmul_rn(iw, ih);
  const float denom = __fsub_rn(__fadd_rn(aa, ab), inter);
  return __fdiv_rn(inter, denom) > 0.5f;
}

__device__ __forceinline__ float rdlane(float v, int src) {
  return __uint_as_float(__builtin_amdgcn_readlane(__float_as_uint(v), src));
}

// cls [B, N, 80] -> clsT [B, 80, N]; tile = 160 anchors x 80 classes.
__global__ __launch_bounds__(TP_T)
void transpose_kernel(const float* __restrict__ cls, float* __restrict__ clsT)
{
  const int blk  = blockIdx.x;           // b * 125 + tile
  const int b    = blk / 125;
  const int tile = blk - b * 125;
  const int n0   = tile * TILE_A;
  const int t    = threadIdx.x;

  __shared__ float4 lds[N_CLS * 41];     // 52.5 KB

  const float4* in4 =
      reinterpret_cast<const float4*>(cls + ((size_t)b * N_ANCH + n0) * N_CLS);
  float* ldsF = reinterpret_cast<float*>(lds);

#pragma unroll
  for (int i = 0; i < 10; ++i) {
    const int f4 = t + i * TP_T;         // < 3200
    const float4 v = in4[f4];
    const int a  = f4 / 20;              // anchor within tile
    const int c0 = (f4 - a * 20) * 4;    // class of v.x
    ldsF[(c0 + 0) * 164 + a] = v.x;
    ldsF[(c0 + 1) * 164 + a] = v.y;
    ldsF[(c0 + 2) * 164 + a] = v.z;
    ldsF[(c0 + 3) * 164 + a] = v.w;
  }
  __syncthreads();

  float4* out4 = reinterpret_cast<float4*>(clsT + (size_t)b * N_CLS * N_ANCH);
#pragma unroll
  for (int i = 0; i < 10; ++i) {
    const int f4 = t + i * TP_T;         // < 3200
    const int c  = f4 / 40;              // 40 float4 per class row
    const int a4 = f4 - c * 40;
    out4[(size_t)c * (N_ANCH / 4) + (n0 / 4) + a4] = lds[c * 41 + a4];
  }
}

// One block per (image, class). Sorted-candidate greedy NMS (exact):
// candidate suppressed iff IOU>0.5 with an already-picked box.
__global__ __launch_bounds__(NMS_T)
void nms_kernel(const float* __restrict__ boxes,
                const float* __restrict__ cls,
                const float* __restrict__ clsT,
                uint4* __restrict__ picks, int useT)
{
  const int bc  = blockIdx.x;
  const int b   = bc / N_CLS;
  const int c   = bc - b * N_CLS;
  const int tid = threadIdx.x;

  const float4* boxesB = reinterpret_cast<const float4*>(boxes) + (size_t)b * N_ANCH;

  __shared__ unsigned long long keys[SORTN];   // 8 KB
  __shared__ unsigned histo[NB];               // 4 KB (becomes suffix-sum)
  __shared__ int sh_cnt, sh_np, sh_bt;

  for (int i = tid; i < NB; i += NMS_T) histo[i] = 0;
  if (tid == 0) sh_np = 0;
  __syncthreads();

  // ---- Phase 1: read scores (regs), build histogram ----
  // element j for reg (k,m): j = ((tid + ((k>>2)<<9)) << 2) + (k&3)
  float sc[ELEMS];
  if (useT) {
    const float4* cT4 =
        reinterpret_cast<const float4*>(clsT + (size_t)bc * N_ANCH);
#pragma unroll
    for (int k = 0; k < 10; ++k) {
      const int f4 = tid + (k << 9);
      float4 v = make_float4(-1.f, -1.f, -1.f, -1.f);
      if (f4 < N_ANCH / 4) v = cT4[f4];
#pragma unroll
      for (int m = 0; m < 4; ++m) {
        const float t = (&v.x)[m];
        const float val = (t > 0.05f) ? t : -1.0f;
        sc[k * 4 + m] = val;
        if (val > 0.0f) {
          int bk = (int)(__float_as_uint(val) >> 16) - BUCKET_BASE;
          if (bk > NB - 1) bk = NB - 1;
          atomicAdd(&histo[bk], 1u);
        }
      }
    }
  } else {
    const float* clsB = cls + ((size_t)b * N_ANCH) * N_CLS + c;
#pragma unroll
    for (int k = 0; k < 10; ++k) {
      const int f4 = tid + (k << 9);
#pragma unroll
      for (int m = 0; m < 4; ++m) {
        const int j = (f4 << 2) + m;
        float val = -1.0f;
        if (j < N_ANCH) {
          const float t = clsB[(size_t)j * N_CLS];
          if (t > 0.05f) val = t;
        }
        sc[k * 4 + m] = val;
        if (val > 0.0f) {
          int bk = (int)(__float_as_uint(val) >> 16) - BUCKET_BASE;
          if (bk > NB - 1) bk = NB - 1;
          atomicAdd(&histo[bk], 1u);
        }
      }
    }
  }
  __syncthreads();

  // ---- Phase 2: suffix sum: histo[i] = #elems in buckets >= i ----
  for (int d = 1; d < NB; d <<= 1) {
    const int i0 = tid, i1 = tid + NMS_T;
    const unsigned a0 = (i0 + d < NB) ? histo[i0 + d] : 0u;
    const unsigned a1 = (i1 + d < NB) ? histo[i1 + d] : 0u;
    __syncthreads();
    histo[i0] += a0; histo[i1] += a1;
    __syncthreads();
  }

  // ---- Selection rounds (expected: exactly one) ----
  int btPrev = NB;
  unsigned processed = 0;

  // picked-box state, distributed across wave 0's lanes (5 static slots)
  float4 pb0, pb1, pb2, pb3, pb4;
  float  pa0 = 0, pa1 = 0, pa2 = 0, pa3 = 0, pa4 = 0;
  pb0 = pb1 = pb2 = pb3 = pb4 = make_float4(0, 0, 0, 0);
  int np = 0;  // live in wave 0 (uniform there)

  while (true) {
    if (tid == 0) { sh_bt = 0; sh_cnt = 0; }
    __syncthreads();
    for (int i = tid; i < NB; i += NMS_T) {
      if (i < btPrev) {
        const unsigned rem  = histo[i] - processed;
        const unsigned remN = (i + 1 < btPrev) ? (histo[i + 1] - processed) : 0u;
        if (rem >= KSEL && remN < KSEL) sh_bt = i;
      }
    }
    __syncthreads();
    const int bt = sh_bt;

    // compact keys with bucket in [lo, btPrev)
    int lo = bt;
#pragma unroll
    for (int k = 0; k < ELEMS; ++k) {
      const float v = sc[k];
      if (v > 0.0f) {
        int bk = (int)(__float_as_uint(v) >> 16) - BUCKET_BASE;
        if (bk > NB - 1) bk = NB - 1;
        if (bk >= lo && bk < btPrev) {
          const int pos = atomicAdd(&sh_cnt, 1);
          if (pos < SORTN) {
            const int j = ((tid + ((k >> 2) << 9)) << 2) + (k & 3);
            keys[pos] = ((unsigned long long)__float_as_uint(v) << 16)
                      | (unsigned long long)(0xFFFFu - (unsigned)j);
          }
        }
      }
    }
    __syncthreads();
    int btEff = bt;
    if (sh_cnt > SORTN && bt + 1 < btPrev) {
      if (tid == 0) sh_cnt = 0;
      __syncthreads();
      lo = bt + 1;
#pragma unroll
      for (int k = 0; k < ELEMS; ++k) {
        const float v = sc[k];
        if (v > 0.0f) {
          int bk = (int)(__float_as_uint(v) >> 16) - BUCKET_BASE;
          if (bk > NB - 1) bk = NB - 1;
          if (bk >= lo && bk < btPrev) {
            const int pos = atomicAdd(&sh_cnt, 1);
            if (pos < SORTN) {
              const int j = ((tid + ((k >> 2) << 9)) << 2) + (k & 3);
              keys[pos] = ((unsigned long long)__float_as_uint(v) << 16)
                        | (unsigned long long)(0xFFFFu - (unsigned)j);
            }
          }
        }
      }
      __syncthreads();
      btEff = bt + 1;
    }
    const int cnt = sh_cnt < SORTN ? sh_cnt : SORTN;

    if (cnt == 0) {
      if (btEff == 0) break;
      processed = histo[btEff]; btPrev = btEff;
      continue;
    }
    for (int i = cnt + tid; i < SORTN; i += NMS_T) keys[i] = 0ull;
    __syncthreads();

    // ---- bitonic sort 1024, descending (zeros sink) ----
    for (int kk = 2; kk <= SORTN; kk <<= 1) {
      for (int jj = kk >> 1; jj > 0; jj >>= 1) {
        for (int i = tid; i < SORTN; i += NMS_T) {
          const int l = i ^ jj;
          if (l > i) {
            const unsigned long long a = keys[i], bv = keys[l];
            const bool up = ((i & kk) == 0);
            if (up ? (a < bv) : (a > bv)) { keys[i] = bv; keys[l] = a; }
          }
        }
        __syncthreads();
      }
    }

    // ---- streaming greedy scan, register pick-state (wave 0 only) ----
    // Candidate boxes prefetched 64-ahead into per-lane regs; broadcast via
    // readlane; each lane tests the candidate against its 5 pick slots.
    if (tid < 64) {
      const int lane = tid;
      int i = 0;
      unsigned long long curKey = 0ull;
      float4 curBox = make_float4(0.f, 0.f, 0.f, 0.f);
      float curArea = 0.f;
      int curIdx = 0;
      if (lane < cnt) {
        curKey = keys[lane];
        curIdx = 0xFFFF - (int)(curKey & 0xFFFFull);
        curBox = boxesB[curIdx];
        curArea = box_area(curBox);
      }
      while (i < cnt && np < MAXDET) {
        const int nb = i + 64;
        unsigned long long nKey = 0ull;
        float4 nBox = make_float4(0.f, 0.f, 0.f, 0.f);
        float nArea = 0.f;
        int nIdx = 0;
        if (nb + lane < cnt) {            // prefetch next batch
          nKey = keys[nb + lane];
          nIdx = 0xFFFF - (int)(nKey & 0xFFFFull);
          nBox = boxesB[nIdx];
          nArea = box_area(nBox);
        }
        const int lim = (cnt < nb) ? cnt : nb;
        for (; i < lim && np < MAXDET; ++i) {
          const int src = i & 63;
          const float4 cb = make_float4(rdlane(curBox.x, src), rdlane(curBox.y, src),
                                        rdlane(curBox.z, src), rdlane(curBox.w, src));
          const float ca = rdlane(curArea, src);
          bool sup = false;
          if (lane       < np) sup  = iou_gt_half(cb, ca, pb0, pa0);
          if (lane +  64 < np) sup |= iou_gt_half(cb, ca, pb1, pa1);
          if (lane + 128 < np) sup |= iou_gt_half(cb, ca, pb2, pa2);
          if (lane + 192 < np) sup |= iou_gt_half(cb, ca, pb3, pa3);
          if (lane + 256 < np) sup |= iou_gt_half(cb, ca, pb4, pa4);
          if (!__any(sup)) {
            const int slot = np >> 6, owner = np & 63;
            if (lane == owner) {
              if      (slot == 0) { pb0 = cb; pa0 = ca; }
              else if (slot == 1) { pb1 = cb; pa1 = ca; }
              else if (slot == 2) { pb2 = cb; pa2 = ca; }
              else if (slot == 3) { pb3 = cb; pa3 = ca; }
              else                { pb4 = cb; pa4 = ca; }
            }
            if (lane == src) {
              const unsigned sbits = (unsigned)(curKey >> 16);
              const unsigned long long pk =
                  ((unsigned long long)sbits << 32) |
                  (unsigned long long)(0xFFFFFFFFu - (unsigned)(c * MAXDET + np));
              picks[(size_t)bc * MAXDET + np] =
                  make_uint4((unsigned)(pk & 0xFFFFFFFFull), (unsigned)(pk >> 32),
                             (unsigned)curIdx, 0u);
            }
            ++np;
          }
        }
        curKey = nKey; curBox = nBox; curArea = nArea; curIdx = nIdx;
      }
      if (lane == 0) sh_np = np;
    }
    __syncthreads();
    if (sh_np >= MAXDET || btEff == 0) break;
    processed = histo[btEff]; btPrev = btEff;
  }
  __syncthreads();

  const int npF = sh_np;
  for (int r = npF + tid; r < MAXDET; r += NMS_T) {
    picks[(size_t)bc * MAXDET + r] = make_uint4(0u, 0u, 0u, 0u);
  }
}

// 160 blocks: build per-image coarse histogram of pick keys in global memory.
__global__ __launch_bounds__(256)
void merge_hist_kernel(const uint4* __restrict__ picks, unsigned* __restrict__ gHist)
{
  const int bc = blockIdx.x;
  const int b  = bc / N_CLS;
  const uint4* base = picks + (size_t)bc * MAXDET;
  for (int i = threadIdx.x; i < MAXDET; i += 256) {
    const uint4 e = base[i];
    const unsigned long long key = ((unsigned long long)e.y << 32) | e.x;
    if (key != 0ull) {
      int bk = (int)(key >> 48) - BUCKET_BASE;
      if (bk > NB - 1) bk = NB - 1;
      if (bk < 0) bk = 0;
      atomicAdd(&gHist[b * NB + bk], 1u);
    }
  }
}

// One block per image: exact top-300 via (prebuilt coarse) + fine histogram
// select + 1024 bitonic sort (stable tie-break lives in the key).
__global__ __launch_bounds__(512)
void topk_merge_kernel(const uint4* __restrict__ picks,
                       const unsigned* __restrict__ gHist,
                       const float* __restrict__ boxes,
                       float* __restrict__ out, int B)
{
  const int b   = blockIdx.x;
  const int tid = threadIdx.x;
  const uint4* pk = picks + (size_t)b * N_CLS * MAXDET;
  const int TOT = N_CLS * MAXDET;

  __shared__ unsigned long long mk[MSORT];
  __shared__ unsigned ma_[MSORT];
  __shared__ unsigned histo[NB];
  __shared__ unsigned histo2[256];
  __shared__ int sh_cnt, sh_b1, sh_b2;

  for (int i = tid; i < NB; i += 512) histo[i] = gHist[b * NB + i];
  if (tid < 256) histo2[tid] = 0;
  if (tid == 0) { sh_cnt = 0; sh_b1 = -1; sh_b2 = 0; }
  __syncthreads();

  // suffix sum (1024 entries, 512 threads)
  for (int d = 1; d < NB; d <<= 1) {
    const int i0 = tid, i1 = tid + 512;
    const unsigned a0 = (i0 + d < NB) ? histo[i0 + d] : 0u;
    const unsigned a1 = (i1 + d < NB) ? histo[i1 + d] : 0u;
    __syncthreads();
    histo[i0] += a0; histo[i1] += a1;
    __syncthreads();
  }
  const unsigned total = histo[0];

  int b1 = -1, b2 = 0;
  if (total > MAXDET) {
    for (int i = tid; i < NB; i += 512) {
      const unsigned rem  = histo[i];
      const unsigned remN = (i + 1 < NB) ? histo[i + 1] : 0u;
      if (rem >= MAXDET && remN < MAXDET) sh_b1 = i;
    }
    __syncthreads();
    b1 = sh_b1;
    const unsigned above = (b1 + 1 < NB) ? histo[b1 + 1] : 0u;
    const unsigned need2 = MAXDET - above;
    for (int i = tid; i < TOT; i += 512) {
      const uint4 e = pk[i];
      const unsigned long long key = ((unsigned long long)e.y << 32) | e.x;
      if (key != 0ull) {
        int bk = (int)(key >> 48) - BUCKET_BASE;
        if (bk > NB - 1) bk = NB - 1;
        if (bk < 0) bk = 0;
        if (bk == b1) atomicAdd(&histo2[(unsigned)(key >> 40) & 0xFFu], 1u);
      }
    }
    __syncthreads();
    for (int d = 1; d < 256; d <<= 1) {
      unsigned a0 = 0;
      if (tid < 256) a0 = (tid + d < 256) ? histo2[tid + d] : 0u;
      __syncthreads();
      if (tid < 256) histo2[tid] += a0;
      __syncthreads();
    }
    for (int i = tid; i < 256; i += 512) {
      const unsigned rem  = histo2[i];
      const unsigned remN = (i + 1 < 256) ? histo2[i + 1] : 0u;
      if (rem >= need2 && remN < need2) sh_b2 = i;
    }
    __syncthreads();
    b2 = sh_b2;
  }

  for (int i = tid; i < MSORT; i += 512) mk[i] = 0ull;
  __syncthreads();
  for (int i = tid; i < TOT; i += 512) {
    const uint4 e = pk[i];
    const unsigned long long key = ((unsigned long long)e.y << 32) | e.x;
    if (key != 0ull) {
      int k1 = (int)(key >> 48) - BUCKET_BASE;
      if (k1 > NB - 1) k1 = NB - 1;
      if (k1 < 0) k1 = 0;
      const int k2 = (int)((key >> 40) & 0xFFull);
      if (k1 > b1 || (k1 == b1 && k2 >= b2)) {
        const int pos = atomicAdd(&sh_cnt, 1);
        if (pos < MSORT) { mk[pos] = key; ma_[pos] = e.z; }
      }
    }
  }
  __syncthreads();

  for (int kk = 2; kk <= MSORT; kk <<= 1) {
    for (int jj = kk >> 1; jj > 0; jj >>= 1) {
      for (int i = tid; i < MSORT; i += 512) {
        const int l = i ^ jj;
        if (l > i) {
          const unsigned long long a = mk[i], bv = mk[l];
          const bool up = ((i & kk) == 0);
          if (up ? (a < bv) : (a > bv)) {
            mk[i] = bv; mk[l] = a;
            const unsigned t = ma_[i]; ma_[i] = ma_[l]; ma_[l] = t;
          }
        }
      }
      __syncthreads();
    }
  }

  float* outBoxes  = out;
  float* outScores = out + (size_t)B * MAXDET * 4;
  float* outLabels = out + (size_t)B * MAXDET * 5;
  for (int r = tid; r < MAXDET; r += 512) {
    const unsigned long long key = mk[r];
    const size_t o = (size_t)b * MAXDET + r;
    if (key == 0ull) {
      reinterpret_cast<float4*>(outBoxes)[o] = make_float4(-1.f, -1.f, -1.f, -1.f);
      outScores[o] = -1.f;
      outLabels[o] = -1.f;
    } else {
      const unsigned posFlat = 0xFFFFFFFFu - (unsigned)(key & 0xFFFFFFFFull);
      const int ccls = (int)(posFlat / MAXDET);
      reinterpret_cast<float4*>(outBoxes)[o] =
          reinterpret_cast<const float4*>(boxes)[(size_t)b * N_ANCH + ma_[r]];
      outScores[o] = __uint_as_float((unsigned)(key >> 32));
      outLabels[o] = (float)ccls;
    }
  }
}

extern "C" void kernel_launch(void* const* d_in, const int* in_sizes, int n_in,
                              void* d_out, int out_size, void* d_ws, size_t ws_size,
                              hipStream_t stream)
{
  const float* boxes = (const float*)d_in[0];
  const float* cls   = (const float*)d_in[1];
  const int B = in_sizes[0] / (N_ANCH * 4);  // = 2

  // ws layout: picks [B*C*300] uint4 | gHist [B*1024] u32 | clsT [B,80,N] f32
  const size_t picksBytes = (size_t)B * N_CLS * MAXDET * sizeof(uint4);
  const size_t ghistBytes = (size_t)B * NB * sizeof(unsigned);
  const size_t clsTBytes  = (size_t)B * N_CLS * N_ANCH * sizeof(float);
  uint4*    picks = (uint4*)d_ws;
  unsigned* gHist = (unsigned*)((char*)d_ws + picksBytes);
  float*    clsT  = (float*)((char*)d_ws + picksBytes + ghistBytes);
  const int useT = (ws_size >= picksBytes + ghistBytes + clsTBytes) ? 1 : 0;

  hipMemsetAsync(gHist, 0, ghistBytes, stream);
  if (useT) {
    transpose_kernel<<<dim3(B * (N_ANCH / TILE_A)), dim3(TP_T), 0, stream>>>(cls, clsT);
  }
  nms_kernel<<<dim3(B * N_CLS), dim3(NMS_T), 0, stream>>>(boxes, cls, clsT, picks, useT);
  merge_hist_kernel<<<dim3(B * N_CLS), dim3(256), 0, stream>>>(picks, gHist);
  topk_merge_kernel<<<dim3(B), dim3(512), 0, stream>>>(picks, gHist, boxes, (float*)d_out, B);
}

// Round 8
// 339.294 us; speedup vs baseline: 1.7285x; 1.7285x over previous
//
#include <hip/hip_runtime.h>
#include <cstdint>
#include <cstddef>

#define N_ANCH 20000
#define N_CLS  80
#define MAXDET 300
#define NMS_T  512
#define ELEMS  40      // scores per thread (40 = 10 float4)
#define SORTN  1024    // NMS bitonic sort size (pow2)
#define KSEL   896     // target top-K per selection round
#define NB     1024    // coarse histogram buckets (564 used; pow2)
#define MSORT  1024    // merge sort size
#define BUCKET_BASE 0x3D4C  // float bits of ~0.05 >> 16

#define TP_T   320     // transpose threads
#define TILE_A 160     // anchors per transpose tile (20000 = 125 * 160)

__device__ __forceinline__ float box_area(float4 b) {
  return __fmul_rn(__fsub_rn(b.z, b.x), __fsub_rn(b.w, b.y));
}

// IOU, unfused IEEE ops, exactly the reference's association order.
// a = candidate (its area first in denom), b = picked/selected.
__device__ __forceinline__ bool iou_gt_half(float4 a, float aa, float4 b, float ab) {
  const float xx1 = fmaxf(a.x, b.x);
  const float yy1 = fmaxf(a.y, b.y);
  const float xx2 = fminf(a.z, b.z);
  const float yy2 = fminf(a.w, b.w);
  const float iw  = fmaxf(__fsub_rn(xx2, xx1), 0.0f);
  const float ih  = fmaxf(__fsub_rn(yy2, yy1), 0.0f);
  const float inter = __fmul_rn(iw, ih);
  const float denom = __fsub_rn(__fadd_rn(aa, ab), inter);
  return __fdiv_rn(inter, denom) > 0.5f;
}

__device__ __forceinline__ float rdlane(float v, int src) {
  return __uint_as_float(__builtin_amdgcn_readlane(__float_as_uint(v), src));
}

// cls [B, N, 80] -> clsT [B, 80, N]; tile = 160 anchors x 80 classes.
__global__ __launch_bounds__(TP_T)
void transpose_kernel(const float* __restrict__ cls, float* __restrict__ clsT)
{
  const int blk  = blockIdx.x;           // b * 125 + tile
  const int b    = blk / 125;
  const int tile = blk - b * 125;
  const int n0   = tile * TILE_A;
  const int t    = threadIdx.x;

  __shared__ float4 lds[N_CLS * 41];     // 52.5 KB

  const float4* in4 =
      reinterpret_cast<const float4*>(cls + ((size_t)b * N_ANCH + n0) * N_CLS);
  float* ldsF = reinterpret_cast<float*>(lds);

#pragma unroll
  for (int i = 0; i < 10; ++i) {
    const int f4 = t + i * TP_T;         // < 3200
    const float4 v = in4[f4];
    const int a  = f4 / 20;              // anchor within tile
    const int c0 = (f4 - a * 20) * 4;    // class of v.x
    ldsF[(c0 + 0) * 164 + a] = v.x;
    ldsF[(c0 + 1) * 164 + a] = v.y;
    ldsF[(c0 + 2) * 164 + a] = v.z;
    ldsF[(c0 + 3) * 164 + a] = v.w;
  }
  __syncthreads();

  float4* out4 = reinterpret_cast<float4*>(clsT + (size_t)b * N_CLS * N_ANCH);
#pragma unroll
  for (int i = 0; i < 10; ++i) {
    const int f4 = t + i * TP_T;         // < 3200
    const int c  = f4 / 40;              // 40 float4 per class row
    const int a4 = f4 - c * 40;
    out4[(size_t)c * (N_ANCH / 4) + (n0 / 4) + a4] = lds[c * 41 + a4];
  }
}

// One block per (image, class). Sorted-candidate greedy NMS (exact):
// candidate suppressed iff IOU>0.5 with an already-picked box.
__global__ __launch_bounds__(NMS_T)
void nms_kernel(const float* __restrict__ boxes,
                const float* __restrict__ cls,
                const float* __restrict__ clsT,
                uint4* __restrict__ picks, int useT)
{
  const int bc  = blockIdx.x;
  const int b   = bc / N_CLS;
  const int c   = bc - b * N_CLS;
  const int tid = threadIdx.x;

  const float4* boxesB = reinterpret_cast<const float4*>(boxes) + (size_t)b * N_ANCH;

  __shared__ unsigned long long keys[SORTN];   // 8 KB
  __shared__ unsigned histo[NB];               // 4 KB (becomes suffix-sum)
  __shared__ int sh_cnt, sh_np, sh_bt;

  for (int i = tid; i < NB; i += NMS_T) histo[i] = 0;
  if (tid == 0) sh_np = 0;
  __syncthreads();

  // ---- Phase 1: read scores (regs), build histogram ----
  // element j for reg (k,m): j = ((tid + ((k>>2)<<9)) << 2) + (k&3)
  float sc[ELEMS];
  if (useT) {
    const float4* cT4 =
        reinterpret_cast<const float4*>(clsT + (size_t)bc * N_ANCH);
#pragma unroll
    for (int k = 0; k < 10; ++k) {
      const int f4 = tid + (k << 9);
      float4 v = make_float4(-1.f, -1.f, -1.f, -1.f);
      if (f4 < N_ANCH / 4) v = cT4[f4];
#pragma unroll
      for (int m = 0; m < 4; ++m) {
        const float t = (&v.x)[m];
        const float val = (t > 0.05f) ? t : -1.0f;
        sc[k * 4 + m] = val;
        if (val > 0.0f) {
          int bk = (int)(__float_as_uint(val) >> 16) - BUCKET_BASE;
          if (bk > NB - 1) bk = NB - 1;
          atomicAdd(&histo[bk], 1u);
        }
      }
    }
  } else {
    const float* clsB = cls + ((size_t)b * N_ANCH) * N_CLS + c;
#pragma unroll
    for (int k = 0; k < 10; ++k) {
      const int f4 = tid + (k << 9);
#pragma unroll
      for (int m = 0; m < 4; ++m) {
        const int j = (f4 << 2) + m;
        float val = -1.0f;
        if (j < N_ANCH) {
          const float t = clsB[(size_t)j * N_CLS];
          if (t > 0.05f) val = t;
        }
        sc[k * 4 + m] = val;
        if (val > 0.0f) {
          int bk = (int)(__float_as_uint(val) >> 16) - BUCKET_BASE;
          if (bk > NB - 1) bk = NB - 1;
          atomicAdd(&histo[bk], 1u);
        }
      }
    }
  }
  __syncthreads();

  // ---- Phase 2: suffix sum: histo[i] = #elems in buckets >= i ----
  for (int d = 1; d < NB; d <<= 1) {
    const int i0 = tid, i1 = tid + NMS_T;
    const unsigned a0 = (i0 + d < NB) ? histo[i0 + d] : 0u;
    const unsigned a1 = (i1 + d < NB) ? histo[i1 + d] : 0u;
    __syncthreads();
    histo[i0] += a0; histo[i1] += a1;
    __syncthreads();
  }

  // ---- Selection rounds (expected: exactly one) ----
  int btPrev = NB;
  unsigned processed = 0;

  // picked-box state, distributed across wave 0's lanes (5 static slots)
  float4 pb0, pb1, pb2, pb3, pb4;
  float  pa0 = 0, pa1 = 0, pa2 = 0, pa3 = 0, pa4 = 0;
  pb0 = pb1 = pb2 = pb3 = pb4 = make_float4(0, 0, 0, 0);
  int np = 0;  // live in wave 0 (uniform there)

  while (true) {
    if (tid == 0) { sh_bt = 0; sh_cnt = 0; }
    __syncthreads();
    for (int i = tid; i < NB; i += NMS_T) {
      if (i < btPrev) {
        const unsigned rem  = histo[i] - processed;
        const unsigned remN = (i + 1 < btPrev) ? (histo[i + 1] - processed) : 0u;
        if (rem >= KSEL && remN < KSEL) sh_bt = i;
      }
    }
    __syncthreads();
    const int bt = sh_bt;

    // compact keys with bucket in [lo, btPrev)
    int lo = bt;
#pragma unroll
    for (int k = 0; k < ELEMS; ++k) {
      const float v = sc[k];
      if (v > 0.0f) {
        int bk = (int)(__float_as_uint(v) >> 16) - BUCKET_BASE;
        if (bk > NB - 1) bk = NB - 1;
        if (bk >= lo && bk < btPrev) {
          const int pos = atomicAdd(&sh_cnt, 1);
          if (pos < SORTN) {
            const int j = ((tid + ((k >> 2) << 9)) << 2) + (k & 3);
            keys[pos] = ((unsigned long long)__float_as_uint(v) << 16)
                      | (unsigned long long)(0xFFFFu - (unsigned)j);
          }
        }
      }
    }
    __syncthreads();
    int btEff = bt;
    if (sh_cnt > SORTN && bt + 1 < btPrev) {
      if (tid == 0) sh_cnt = 0;
      __syncthreads();
      lo = bt + 1;
#pragma unroll
      for (int k = 0; k < ELEMS; ++k) {
        const float v = sc[k];
        if (v > 0.0f) {
          int bk = (int)(__float_as_uint(v) >> 16) - BUCKET_BASE;
          if (bk > NB - 1) bk = NB - 1;
          if (bk >= lo && bk < btPrev) {
            const int pos = atomicAdd(&sh_cnt, 1);
            if (pos < SORTN) {
              const int j = ((tid + ((k >> 2) << 9)) << 2) + (k & 3);
              keys[pos] = ((unsigned long long)__float_as_uint(v) << 16)
                        | (unsigned long long)(0xFFFFu - (unsigned)j);
            }
          }
        }
      }
      __syncthreads();
      btEff = bt + 1;
    }
    const int cnt = sh_cnt < SORTN ? sh_cnt : SORTN;

    if (cnt == 0) {
      if (btEff == 0) break;
      processed = histo[btEff]; btPrev = btEff;
      continue;
    }
    for (int i = cnt + tid; i < SORTN; i += NMS_T) keys[i] = 0ull;
    __syncthreads();

    // ---- bitonic sort 1024, descending (zeros sink) ----
    for (int kk = 2; kk <= SORTN; kk <<= 1) {
      for (int jj = kk >> 1; jj > 0; jj >>= 1) {
        for (int i = tid; i < SORTN; i += NMS_T) {
          const int l = i ^ jj;
          if (l > i) {
            const unsigned long long a = keys[i], bv = keys[l];
            const bool up = ((i & kk) == 0);
            if (up ? (a < bv) : (a > bv)) { keys[i] = bv; keys[l] = a; }
          }
        }
        __syncthreads();
      }
    }

    // ---- streaming greedy scan, register pick-state (wave 0 only) ----
    if (tid < 64) {
      const int lane = tid;
      int i = 0;
      unsigned long long curKey = 0ull;
      float4 curBox = make_float4(0.f, 0.f, 0.f, 0.f);
      float curArea = 0.f;
      int curIdx = 0;
      if (lane < cnt) {
        curKey = keys[lane];
        curIdx = 0xFFFF - (int)(curKey & 0xFFFFull);
        curBox = boxesB[curIdx];
        curArea = box_area(curBox);
      }
      while (i < cnt && np < MAXDET) {
        const int nb = i + 64;
        unsigned long long nKey = 0ull;
        float4 nBox = make_float4(0.f, 0.f, 0.f, 0.f);
        float nArea = 0.f;
        int nIdx = 0;
        if (nb + lane < cnt) {            // prefetch next batch
          nKey = keys[nb + lane];
          nIdx = 0xFFFF - (int)(nKey & 0xFFFFull);
          nBox = boxesB[nIdx];
          nArea = box_area(nBox);
        }
        const int lim = (cnt < nb) ? cnt : nb;
        for (; i < lim && np < MAXDET; ++i) {
          const int src = i & 63;
          const float4 cb = make_float4(rdlane(curBox.x, src), rdlane(curBox.y, src),
                                        rdlane(curBox.z, src), rdlane(curBox.w, src));
          const float ca = rdlane(curArea, src);
          bool sup = false;
          if (lane       < np) sup  = iou_gt_half(cb, ca, pb0, pa0);
          if (lane +  64 < np) sup |= iou_gt_half(cb, ca, pb1, pa1);
          if (lane + 128 < np) sup |= iou_gt_half(cb, ca, pb2, pa2);
          if (lane + 192 < np) sup |= iou_gt_half(cb, ca, pb3, pa3);
          if (lane + 256 < np) sup |= iou_gt_half(cb, ca, pb4, pa4);
          if (!__any(sup)) {
            const int slot = np >> 6, owner = np & 63;
            if (lane == owner) {
              if      (slot == 0) { pb0 = cb; pa0 = ca; }
              else if (slot == 1) { pb1 = cb; pa1 = ca; }
              else if (slot == 2) { pb2 = cb; pa2 = ca; }
              else if (slot == 3) { pb3 = cb; pa3 = ca; }
              else                { pb4 = cb; pa4 = ca; }
            }
            if (lane == src) {
              const unsigned sbits = (unsigned)(curKey >> 16);
              const unsigned long long pk =
                  ((unsigned long long)sbits << 32) |
                  (unsigned long long)(0xFFFFFFFFu - (unsigned)(c * MAXDET + np));
              picks[(size_t)bc * MAXDET + np] =
                  make_uint4((unsigned)(pk & 0xFFFFFFFFull), (unsigned)(pk >> 32),
                             (unsigned)curIdx, 0u);
            }
            ++np;
          }
        }
        curKey = nKey; curBox = nBox; curArea = nArea; curIdx = nIdx;
      }
      if (lane == 0) sh_np = np;
    }
    __syncthreads();
    if (sh_np >= MAXDET || btEff == 0) break;
    processed = histo[btEff]; btPrev = btEff;
  }
  __syncthreads();

  const int npF = sh_np;
  for (int r = npF + tid; r < MAXDET; r += NMS_T) {
    picks[(size_t)bc * MAXDET + r] = make_uint4(0u, 0u, 0u, 0u);
  }
}

// One block per image: exact top-300 of the 24000 pick keys via two-level
// in-LDS histogram select + 1024 bitonic sort (stable tie-break in the key).
__global__ __launch_bounds__(512)
void topk_merge_kernel(const uint4* __restrict__ picks,
                       const float* __restrict__ boxes,
                       float* __restrict__ out, int B)
{
  const int b   = blockIdx.x;
  const int tid = threadIdx.x;
  const uint4* pk = picks + (size_t)b * N_CLS * MAXDET;
  const int TOT = N_CLS * MAXDET;

  __shared__ unsigned long long mk[MSORT];
  __shared__ unsigned ma_[MSORT];
  __shared__ unsigned histo[NB];
  __shared__ unsigned histo2[256];
  __shared__ int sh_cnt, sh_b1, sh_b2;

  for (int i = tid; i < NB; i += 512) histo[i] = 0;
  if (tid < 256) histo2[tid] = 0;
  if (tid == 0) { sh_cnt = 0; sh_b1 = -1; sh_b2 = 0; }
  __syncthreads();

  // coarse histogram on score bits [31:16] (LDS atomics)
  for (int i = tid; i < TOT; i += 512) {
    const uint4 e = pk[i];
    const unsigned long long key = ((unsigned long long)e.y << 32) | e.x;
    if (key != 0ull) {
      int bk = (int)(key >> 48) - BUCKET_BASE;
      if (bk > NB - 1) bk = NB - 1;
      if (bk < 0) bk = 0;
      atomicAdd(&histo[bk], 1u);
    }
  }
  __syncthreads();
  // suffix sum (1024 entries, 512 threads)
  for (int d = 1; d < NB; d <<= 1) {
    const int i0 = tid, i1 = tid + 512;
    const unsigned a0 = (i0 + d < NB) ? histo[i0 + d] : 0u;
    const unsigned a1 = (i1 + d < NB) ? histo[i1 + d] : 0u;
    __syncthreads();
    histo[i0] += a0; histo[i1] += a1;
    __syncthreads();
  }
  const unsigned total = histo[0];

  int b1 = -1, b2 = 0;
  if (total > MAXDET) {
    for (int i = tid; i < NB; i += 512) {
      const unsigned rem  = histo[i];
      const unsigned remN = (i + 1 < NB) ? histo[i + 1] : 0u;
      if (rem >= MAXDET && remN < MAXDET) sh_b1 = i;
    }
    __syncthreads();
    b1 = sh_b1;
    const unsigned above = (b1 + 1 < NB) ? histo[b1 + 1] : 0u;
    const unsigned need2 = MAXDET - above;
    for (int i = tid; i < TOT; i += 512) {
      const uint4 e = pk[i];
      const unsigned long long key = ((unsigned long long)e.y << 32) | e.x;
      if (key != 0ull) {
        int bk = (int)(key >> 48) - BUCKET_BASE;
        if (bk > NB - 1) bk = NB - 1;
        if (bk < 0) bk = 0;
        if (bk == b1) atomicAdd(&histo2[(unsigned)(key >> 40) & 0xFFu], 1u);
      }
    }
    __syncthreads();
    for (int d = 1; d < 256; d <<= 1) {
      unsigned a0 = 0;
      if (tid < 256) a0 = (tid + d < 256) ? histo2[tid + d] : 0u;
      __syncthreads();
      if (tid < 256) histo2[tid] += a0;
      __syncthreads();
    }
    for (int i = tid; i < 256; i += 512) {
      const unsigned rem  = histo2[i];
      const unsigned remN = (i + 1 < 256) ? histo2[i + 1] : 0u;
      if (rem >= need2 && remN < need2) sh_b2 = i;
    }
    __syncthreads();
    b2 = sh_b2;
  }

  for (int i = tid; i < MSORT; i += 512) mk[i] = 0ull;
  __syncthreads();
  for (int i = tid; i < TOT; i += 512) {
    const uint4 e = pk[i];
    const unsigned long long key = ((unsigned long long)e.y << 32) | e.x;
    if (key != 0ull) {
      int k1 = (int)(key >> 48) - BUCKET_BASE;
      if (k1 > NB - 1) k1 = NB - 1;
      if (k1 < 0) k1 = 0;
      const int k2 = (int)((key >> 40) & 0xFFull);
      if (k1 > b1 || (k1 == b1 && k2 >= b2)) {
        const int pos = atomicAdd(&sh_cnt, 1);
        if (pos < MSORT) { mk[pos] = key; ma_[pos] = e.z; }
      }
    }
  }
  __syncthreads();

  // bitonic sort 1024 desc, carrying anchors
  for (int kk = 2; kk <= MSORT; kk <<= 1) {
    for (int jj = kk >> 1; jj > 0; jj >>= 1) {
      for (int i = tid; i < MSORT; i += 512) {
        const int l = i ^ jj;
        if (l > i) {
          const unsigned long long a = mk[i], bv = mk[l];
          const bool up = ((i & kk) == 0);
          if (up ? (a < bv) : (a > bv)) {
            mk[i] = bv; mk[l] = a;
            const unsigned t = ma_[i]; ma_[i] = ma_[l]; ma_[l] = t;
          }
        }
      }
      __syncthreads();
    }
  }

  float* outBoxes  = out;
  float* outScores = out + (size_t)B * MAXDET * 4;
  float* outLabels = out + (size_t)B * MAXDET * 5;
  for (int r = tid; r < MAXDET; r += 512) {
    const unsigned long long key = mk[r];
    const size_t o = (size_t)b * MAXDET + r;
    if (key == 0ull) {
      reinterpret_cast<float4*>(outBoxes)[o] = make_float4(-1.f, -1.f, -1.f, -1.f);
      outScores[o] = -1.f;
      outLabels[o] = -1.f;
    } else {
      const unsigned posFlat = 0xFFFFFFFFu - (unsigned)(key & 0xFFFFFFFFull);
      const int ccls = (int)(posFlat / MAXDET);
      reinterpret_cast<float4*>(outBoxes)[o] =
          reinterpret_cast<const float4*>(boxes)[(size_t)b * N_ANCH + ma_[r]];
      outScores[o] = __uint_as_float((unsigned)(key >> 32));
      outLabels[o] = (float)ccls;
    }
  }
}

extern "C" void kernel_launch(void* const* d_in, const int* in_sizes, int n_in,
                              void* d_out, int out_size, void* d_ws, size_t ws_size,
                              hipStream_t stream)
{
  const float* boxes = (const float*)d_in[0];
  const float* cls   = (const float*)d_in[1];
  const int B = in_sizes[0] / (N_ANCH * 4);  // = 2

  // ws layout: picks [B*C*300] uint4 (768 KB), then clsT [B,80,N] (12.8 MB)
  const size_t picksBytes = (size_t)B * N_CLS * MAXDET * sizeof(uint4);
  const size_t clsTBytes  = (size_t)B * N_CLS * N_ANCH * sizeof(float);
  uint4* picks = (uint4*)d_ws;
  float* clsT  = (float*)((char*)d_ws + picksBytes);
  const int useT = (ws_size >= picksBytes + clsTBytes) ? 1 : 0;

  if (useT) {
    transpose_kernel<<<dim3(B * (N_ANCH / TILE_A)), dim3(TP_T), 0, stream>>>(cls, clsT);
  }
  nms_kernel<<<dim3(B * N_CLS), dim3(NMS_T), 0, stream>>>(boxes, cls, clsT, picks, useT);
  topk_merge_kernel<<<dim3(B), dim3(512), 0, stream>>>(picks, boxes, (float*)d_out, B);
}

// Round 10
// 301.846 us; speedup vs baseline: 1.9430x; 1.1241x over previous
//
#include <hip/hip_runtime.h>
#include <cstdint>
#include <cstddef>

#define N_ANCH 20000
#define N_CLS  80
#define MAXDET 300
#define NMS_T  512
#define ELEMS  40      // scores per thread (40 = 10 float4)
#define SORTN  1024    // NMS bitonic sort size (pow2)
#define KSEL   768     // target top-K per selection round
#define NB     1024    // coarse histogram buckets (564 used; pow2)
#define MSORT  1024    // merge sort size
#define MERGE_T 1024   // merge threads
#define BUCKET_BASE 0x3D4C  // float bits of ~0.05 >> 16

#define TP_T   320     // transpose threads
#define TILE_A 160     // anchors per transpose tile (20000 = 125 * 160)

__device__ __forceinline__ float box_area(float4 b) {
  return __fmul_rn(__fsub_rn(b.z, b.x), __fsub_rn(b.w, b.y));
}

// IOU, unfused IEEE ops, exactly the reference's association order.
// a = candidate (its area first in denom), b = picked/selected.
__device__ __forceinline__ bool iou_gt_half(float4 a, float aa, float4 b, float ab) {
  const float xx1 = fmaxf(a.x, b.x);
  const float yy1 = fmaxf(a.y, b.y);
  const float xx2 = fminf(a.z, b.z);
  const float yy2 = fminf(a.w, b.w);
  const float iw  = fmaxf(__fsub_rn(xx2, xx1), 0.0f);
  const float ih  = fmaxf(__fsub_rn(yy2, yy1), 0.0f);
  const float inter = __fmul_rn(iw, ih);
  const float denom = __fsub_rn(__fadd_rn(aa, ab), inter);
  return __fdiv_rn(inter, denom) > 0.5f;
}

// cls [B, N, 80] -> clsT [B, 80, N]; tile = 160 anchors x 80 classes.
__global__ __launch_bounds__(TP_T)
void transpose_kernel(const float* __restrict__ cls, float* __restrict__ clsT)
{
  const int blk  = blockIdx.x;           // b * 125 + tile
  const int b    = blk / 125;
  const int tile = blk - b * 125;
  const int n0   = tile * TILE_A;
  const int t    = threadIdx.x;

  __shared__ float4 lds[N_CLS * 41];     // 52.5 KB

  const float4* in4 =
      reinterpret_cast<const float4*>(cls + ((size_t)b * N_ANCH + n0) * N_CLS);
  float* ldsF = reinterpret_cast<float*>(lds);

#pragma unroll
  for (int i = 0; i < 10; ++i) {
    const int f4 = t + i * TP_T;         // < 3200
    const float4 v = in4[f4];
    const int a  = f4 / 20;              // anchor within tile
    const int c0 = (f4 - a * 20) * 4;    // class of v.x
    ldsF[(c0 + 0) * 164 + a] = v.x;
    ldsF[(c0 + 1) * 164 + a] = v.y;
    ldsF[(c0 + 2) * 164 + a] = v.z;
    ldsF[(c0 + 3) * 164 + a] = v.w;
  }
  __syncthreads();

  float4* out4 = reinterpret_cast<float4*>(clsT + (size_t)b * N_CLS * N_ANCH);
#pragma unroll
  for (int i = 0; i < 10; ++i) {
    const int f4 = t + i * TP_T;         // < 3200
    const int c  = f4 / 40;              // 40 float4 per class row
    const int a4 = f4 - c * 40;
    out4[(size_t)c * (N_ANCH / 4) + (n0 / 4) + a4] = lds[c * 41 + a4];
  }
}

// One block per (image, class). Sorted-candidate greedy NMS (exact):
// candidate suppressed iff IOU>0.5 with an already-picked box.
// Writes SoA picks (keys u64, anchors u32) and adds its picks' coarse-bucket
// counts to the per-image global histogram gHist (spread atomics).
__global__ __launch_bounds__(NMS_T)
void nms_kernel(const float* __restrict__ boxes,
                const float* __restrict__ cls,
                const float* __restrict__ clsT,
                unsigned long long* __restrict__ pKeys,
                unsigned* __restrict__ pAnch,
                unsigned* __restrict__ gHist, int useT)
{
  const int bc  = blockIdx.x;
  const int b   = bc / N_CLS;
  const int c   = bc - b * N_CLS;
  const int tid = threadIdx.x;

  const float4* boxesB = reinterpret_cast<const float4*>(boxes) + (size_t)b * N_ANCH;

  __shared__ unsigned long long keys[SORTN];   // 8 KB
  __shared__ unsigned histo[NB];               // 4 KB (suffix-sum, then reused)
  __shared__ float4 pBox[MAXDET];
  __shared__ float  pArea[MAXDET];
  __shared__ int    pBk[MAXDET];               // coarse bucket of each pick
  __shared__ int sh_cnt, sh_np, sh_bt;

  for (int i = tid; i < NB; i += NMS_T) histo[i] = 0;
  if (tid == 0) sh_np = 0;
  __syncthreads();

  // ---- Phase 1: read scores (regs), build histogram ----
  // element j for reg (k,m): j = ((tid + ((k>>2)<<9)) << 2) + (k&3)
  float sc[ELEMS];
  if (useT) {
    const float4* cT4 =
        reinterpret_cast<const float4*>(clsT + (size_t)bc * N_ANCH);
#pragma unroll
    for (int k = 0; k < 10; ++k) {
      const int f4 = tid + (k << 9);
      float4 v = make_float4(-1.f, -1.f, -1.f, -1.f);
      if (f4 < N_ANCH / 4) v = cT4[f4];
#pragma unroll
      for (int m = 0; m < 4; ++m) {
        const float t = (&v.x)[m];
        const float val = (t > 0.05f) ? t : -1.0f;
        sc[k * 4 + m] = val;
        if (val > 0.0f) {
          int bk = (int)(__float_as_uint(val) >> 16) - BUCKET_BASE;
          if (bk > NB - 1) bk = NB - 1;
          atomicAdd(&histo[bk], 1u);
        }
      }
    }
  } else {
    const float* clsB = cls + ((size_t)b * N_ANCH) * N_CLS + c;
#pragma unroll
    for (int k = 0; k < 10; ++k) {
      const int f4 = tid + (k << 9);
#pragma unroll
      for (int m = 0; m < 4; ++m) {
        const int j = (f4 << 2) + m;
        float val = -1.0f;
        if (j < N_ANCH) {
          const float t = clsB[(size_t)j * N_CLS];
          if (t > 0.05f) val = t;
        }
        sc[k * 4 + m] = val;
        if (val > 0.0f) {
          int bk = (int)(__float_as_uint(val) >> 16) - BUCKET_BASE;
          if (bk > NB - 1) bk = NB - 1;
          atomicAdd(&histo[bk], 1u);
        }
      }
    }
  }
  __syncthreads();

  // ---- Phase 2: suffix sum: histo[i] = #elems in buckets >= i ----
  for (int d = 1; d < NB; d <<= 1) {
    const int i0 = tid, i1 = tid + NMS_T;
    const unsigned a0 = (i0 + d < NB) ? histo[i0 + d] : 0u;
    const unsigned a1 = (i1 + d < NB) ? histo[i1 + d] : 0u;
    __syncthreads();
    histo[i0] += a0; histo[i1] += a1;
    __syncthreads();
  }

  // ---- Selection rounds (expected: exactly one) ----
  int btPrev = NB;
  unsigned processed = 0;

  while (true) {
    if (tid == 0) { sh_bt = 0; sh_cnt = 0; }
    __syncthreads();
    for (int i = tid; i < NB; i += NMS_T) {
      if (i < btPrev) {
        const unsigned rem  = histo[i] - processed;
        const unsigned remN = (i + 1 < btPrev) ? (histo[i + 1] - processed) : 0u;
        if (rem >= KSEL && remN < KSEL) sh_bt = i;
      }
    }
    __syncthreads();
    const int bt = sh_bt;

    // compact keys with bucket in [lo, btPrev)
    int lo = bt;
#pragma unroll
    for (int k = 0; k < ELEMS; ++k) {
      const float v = sc[k];
      if (v > 0.0f) {
        int bk = (int)(__float_as_uint(v) >> 16) - BUCKET_BASE;
        if (bk > NB - 1) bk = NB - 1;
        if (bk >= lo && bk < btPrev) {
          const int pos = atomicAdd(&sh_cnt, 1);
          if (pos < SORTN) {
            const int j = ((tid + ((k >> 2) << 9)) << 2) + (k & 3);
            keys[pos] = ((unsigned long long)__float_as_uint(v) << 16)
                      | (unsigned long long)(0xFFFFu - (unsigned)j);
          }
        }
      }
    }
    __syncthreads();
    int btEff = bt;
    if (sh_cnt > SORTN && bt + 1 < btPrev) {
      if (tid == 0) sh_cnt = 0;
      __syncthreads();
      lo = bt + 1;
#pragma unroll
      for (int k = 0; k < ELEMS; ++k) {
        const float v = sc[k];
        if (v > 0.0f) {
          int bk = (int)(__float_as_uint(v) >> 16) - BUCKET_BASE;
          if (bk > NB - 1) bk = NB - 1;
          if (bk >= lo && bk < btPrev) {
            const int pos = atomicAdd(&sh_cnt, 1);
            if (pos < SORTN) {
              const int j = ((tid + ((k >> 2) << 9)) << 2) + (k & 3);
              keys[pos] = ((unsigned long long)__float_as_uint(v) << 16)
                        | (unsigned long long)(0xFFFFu - (unsigned)j);
            }
          }
        }
      }
      __syncthreads();
      btEff = bt + 1;
    }
    const int cnt = sh_cnt < SORTN ? sh_cnt : SORTN;

    if (cnt == 0) {
      if (btEff == 0) break;
      processed = histo[btEff]; btPrev = btEff;
      continue;
    }
    for (int i = cnt + tid; i < SORTN; i += NMS_T) keys[i] = 0ull;
    __syncthreads();

    // ---- bitonic sort 1024, descending (zeros sink) ----
    for (int kk = 2; kk <= SORTN; kk <<= 1) {
      for (int jj = kk >> 1; jj > 0; jj >>= 1) {
        for (int i = tid; i < SORTN; i += NMS_T) {
          const int l = i ^ jj;
          if (l > i) {
            const unsigned long long a = keys[i], bv = keys[l];
            const bool up = ((i & kk) == 0);
            if (up ? (a < bv) : (a > bv)) { keys[i] = bv; keys[l] = a; }
          }
        }
        __syncthreads();
      }
    }

    // ---- batch-64 wave-parallel greedy scan (wave 0) ----
    if (tid < 64) {
      const int lane = tid;
      int np = sh_np;
      for (int i0 = 0; i0 < cnt && np < MAXDET; i0 += 64) {
        const int ci = i0 + lane;
        const bool haveC = ci < cnt;
        unsigned long long key = 0ull;
        if (haveC) key = keys[ci];
        const int idx = 0xFFFF - (int)(key & 0xFFFFull);
        // candidate key layout: sbits in bits [47:16] -> bucket = key>>32 - BASE
        int myBk = (int)(key >> 32) - BUCKET_BASE;
        if (myBk > NB - 1) myBk = NB - 1;
        if (myBk < 0) myBk = 0;
        float4 cb = make_float4(0.f, 0.f, 0.f, 0.f);
        if (haveC) cb = boxesB[idx];
        const float ca = box_area(cb);
        bool alive = haveC;
        for (int j = 0; j < np; ++j) {
          if (alive && iou_gt_half(cb, ca, pBox[j], pArea[j])) alive = false;
        }
        unsigned long long remM = __ballot(alive);
        while (remM != 0ull && np < MAXDET) {
          const int s = __ffsll(remM) - 1;
          const float bx = __shfl(cb.x, s), by = __shfl(cb.y, s);
          const float bz = __shfl(cb.z, s), bw = __shfl(cb.w, s);
          const float ba = __shfl(ca, s);
          const int   bkp = __shfl(myBk, s);
          if (lane == s) {
            const unsigned sbits = (unsigned)(key >> 16);
            const unsigned long long pk =
                ((unsigned long long)sbits << 32) |
                (unsigned long long)(0xFFFFFFFFu - (unsigned)(c * MAXDET + np));
            pKeys[(size_t)bc * MAXDET + np] = pk;
            pAnch[(size_t)bc * MAXDET + np] = (unsigned)idx;
            alive = false;
          }
          if (lane == 0) {
            pBox[np] = make_float4(bx, by, bz, bw);
            pArea[np] = ba;
            pBk[np] = bkp;
          }
          if (alive && lane > s) {
            if (iou_gt_half(cb, ca, make_float4(bx, by, bz, bw), ba)) alive = false;
          }
          ++np;
          remM = __ballot(alive);
        }
      }
      if (lane == 0) sh_np = np;
    }
    __syncthreads();
    if (sh_np >= MAXDET || btEff == 0) break;
    processed = histo[btEff]; btPrev = btEff;
  }
  __syncthreads();

  const int npF = sh_np;
  // zero tails (invalid picks)
  for (int r = npF + tid; r < MAXDET; r += NMS_T) {
    pKeys[(size_t)bc * MAXDET + r] = 0ull;
    pAnch[(size_t)bc * MAXDET + r] = 0u;
  }
  // rebuild pick-bucket histogram (reuse histo) and add to global per-image
  for (int i = tid; i < NB; i += NMS_T) histo[i] = 0;
  __syncthreads();
  if (tid < npF) atomicAdd(&histo[pBk[tid]], 1u);
  __syncthreads();
  for (int i = tid; i < NB; i += NMS_T) {
    const unsigned v = histo[i];
    if (v) atomicAdd(&gHist[b * NB + i], v);  // ~13 nonzero buckets/class
  }
}

// One block per image, 1024 threads: exact top-300 of the 24000 pick keys.
// Coarse histogram is prebuilt by nms (gHist); two SoA passes + 1024 sort.
__global__ __launch_bounds__(MERGE_T)
void topk_merge_kernel(const unsigned long long* __restrict__ pKeys,
                       const unsigned* __restrict__ pAnch,
                       const unsigned* __restrict__ gHist,
                       const float* __restrict__ boxes,
                       float* __restrict__ out, int B)
{
  const int b   = blockIdx.x;
  const int tid = threadIdx.x;
  const unsigned long long* pk = pKeys + (size_t)b * N_CLS * MAXDET;
  const unsigned* pa = pAnch + (size_t)b * N_CLS * MAXDET;
  const int TOT = N_CLS * MAXDET;

  __shared__ unsigned long long mk[MSORT];   // 8 KB
  __shared__ unsigned ma_[MSORT];            // 4 KB
  __shared__ unsigned histo[NB];             // 4 KB
  __shared__ unsigned histo2[256];           // 1 KB
  __shared__ int sh_cnt, sh_b1, sh_b2;

  histo[tid] = gHist[b * NB + tid];          // tid < 1024 == NB
  if (tid < 256) histo2[tid] = 0;
  if (tid == 0) { sh_cnt = 0; sh_b1 = -1; sh_b2 = 0; }
  __syncthreads();

  // suffix sum over 1024 buckets (one per thread)
  for (int d = 1; d < NB; d <<= 1) {
    const unsigned a0 = (tid + d < NB) ? histo[tid + d] : 0u;
    __syncthreads();
    histo[tid] += a0;
    __syncthreads();
  }
  const unsigned total = histo[0];

  int b1 = -1, b2 = 0;
  if (total > MAXDET) {
    {
      const unsigned rem  = histo[tid];
      const unsigned remN = (tid + 1 < NB) ? histo[tid + 1] : 0u;
      if (rem >= MAXDET && remN < MAXDET) sh_b1 = tid;
    }
    __syncthreads();
    b1 = sh_b1;
    const unsigned above = (b1 + 1 < NB) ? histo[b1 + 1] : 0u;  // < 300
    const unsigned need2 = MAXDET - above;                       // >= 1
    // fine histogram (score bits [15:8]) within boundary bucket b1
    for (int i = tid; i < TOT; i += MERGE_T) {
      const unsigned long long key = pk[i];
      if (key != 0ull) {
        int bk = (int)(key >> 48) - BUCKET_BASE;   // pick key: sbits in [63:32]
        if (bk > NB - 1) bk = NB - 1;
        if (bk < 0) bk = 0;
        if (bk == b1) atomicAdd(&histo2[(unsigned)(key >> 40) & 0xFFu], 1u);
      }
    }
    __syncthreads();
    for (int d = 1; d < 256; d <<= 1) {
      unsigned a0 = 0;
      if (tid < 256) a0 = (tid + d < 256) ? histo2[tid + d] : 0u;
      __syncthreads();
      if (tid < 256) histo2[tid] += a0;
      __syncthreads();
    }
    if (tid < 256) {
      const unsigned rem  = histo2[tid];
      const unsigned remN = (tid + 1 < 256) ? histo2[tid + 1] : 0u;
      if (rem >= need2 && remN < need2) sh_b2 = tid;
    }
    __syncthreads();
    b2 = sh_b2;
  }

  mk[tid] = 0ull;                            // tid < 1024 == MSORT
  __syncthreads();
  for (int i = tid; i < TOT; i += MERGE_T) {
    const unsigned long long key = pk[i];
    if (key != 0ull) {
      int k1 = (int)(key >> 48) - BUCKET_BASE;
      if (k1 > NB - 1) k1 = NB - 1;
      if (k1 < 0) k1 = 0;
      const int k2 = (int)((key >> 40) & 0xFFull);
      if (k1 > b1 || (k1 == b1 && k2 >= b2)) {
        const int pos = atomicAdd(&sh_cnt, 1);
        if (pos < MSORT) { mk[pos] = key; ma_[pos] = pa[i]; }
      }
    }
  }
  __syncthreads();

  // bitonic sort 1024 desc (one element per thread), carrying anchors
  for (int kk = 2; kk <= MSORT; kk <<= 1) {
    for (int jj = kk >> 1; jj > 0; jj >>= 1) {
      const int i = tid;
      const int l = i ^ jj;
      if (l > i) {
        const unsigned long long a = mk[i], bv = mk[l];
        const bool up = ((i & kk) == 0);
        if (up ? (a < bv) : (a > bv)) {
          mk[i] = bv; mk[l] = a;
          const unsigned t = ma_[i]; ma_[i] = ma_[l]; ma_[l] = t;
        }
      }
      __syncthreads();
    }
  }

  float* outBoxes  = out;                            // [B,300,4]
  float* outScores = out + (size_t)B * MAXDET * 4;   // [B,300]
  float* outLabels = out + (size_t)B * MAXDET * 5;   // [B,300] (as float)
  if (tid < MAXDET) {
    const unsigned long long key = mk[tid];
    const size_t o = (size_t)b * MAXDET + tid;
    if (key == 0ull) {
      reinterpret_cast<float4*>(outBoxes)[o] = make_float4(-1.f, -1.f, -1.f, -1.f);
      outScores[o] = -1.f;
      outLabels[o] = -1.f;
    } else {
      const unsigned posFlat = 0xFFFFFFFFu - (unsigned)(key & 0xFFFFFFFFull);
      const int ccls = (int)(posFlat / MAXDET);
      reinterpret_cast<float4*>(outBoxes)[o] =
          reinterpret_cast<const float4*>(boxes)[(size_t)b * N_ANCH + ma_[tid]];
      outScores[o] = __uint_as_float((unsigned)(key >> 32));
      outLabels[o] = (float)ccls;
    }
  }
}

extern "C" void kernel_launch(void* const* d_in, const int* in_sizes, int n_in,
                              void* d_out, int out_size, void* d_ws, size_t ws_size,
                              hipStream_t stream)
{
  const float* boxes = (const float*)d_in[0];
  const float* cls   = (const float*)d_in[1];
  const int B = in_sizes[0] / (N_ANCH * 4);  // = 2

  // ws layout: pKeys u64 | pAnch u32 | gHist u32[B*1024] | clsT [B,80,N] f32
  const size_t keysBytes  = (size_t)B * N_CLS * MAXDET * sizeof(unsigned long long);
  const size_t anchBytes  = (size_t)B * N_CLS * MAXDET * sizeof(unsigned);
  const size_t ghistBytes = (size_t)B * NB * sizeof(unsigned);
  const size_t clsTBytes  = (size_t)B * N_CLS * N_ANCH * sizeof(float);
  unsigned long long* pKeys = (unsigned long long*)d_ws;
  unsigned* pAnch = (unsigned*)((char*)d_ws + keysBytes);
  unsigned* gHist = (unsigned*)((char*)d_ws + keysBytes + anchBytes);
  float*    clsT  = (float*)((char*)d_ws + keysBytes + anchBytes + ghistBytes);
  const int useT =
      (ws_size >= keysBytes + anchBytes + ghistBytes + clsTBytes) ? 1 : 0;

  hipMemsetAsync(gHist, 0, ghistBytes, stream);
  if (useT) {
    transpose_kernel<<<dim3(B * (N_ANCH / TILE_A)), dim3(TP_T), 0, stream>>>(cls, clsT);
  }
  nms_kernel<<<dim3(B * N_CLS), dim3(NMS_T), 0, stream>>>(
      boxes, cls, clsT, pKeys, pAnch, gHist, useT);
  topk_merge_kernel<<<dim3(B), dim3(MERGE_T), 0, stream>>>(
      pKeys, pAnch, gHist, boxes, (float*)d_out, B);
}

// Round 11
// 293.504 us; speedup vs baseline: 1.9982x; 1.0284x over previous
//
#include <hip/hip_runtime.h>
#include <cstdint>
#include <cstddef>

#define N_ANCH 20000
#define N_CLS  80
#define MAXDET 300
#define NMS_T  512
#define ELEMS  40      // scores per thread in select (10 float4)
#define SORTN  1024    // bitonic sort size (pow2)
#define KSEL   768     // target top-K per selection round
#define NB     1024    // coarse histogram buckets (564 used; pow2)
#define MSORT  1024    // merge sort size
#define MERGE_T 1024   // merge threads
#define BUCKET_BASE 0x3D4C  // float bits of ~0.05 >> 16

#define TP_T   320     // transpose threads
#define TILE_A 160     // anchors per transpose tile (20000 = 125 * 160)

__device__ __forceinline__ float box_area(float4 b) {
  return __fmul_rn(__fsub_rn(b.z, b.x), __fsub_rn(b.w, b.y));
}

// IOU, unfused IEEE ops, exactly the reference's association order.
// a = candidate (its area first in denom), b = picked/selected.
__device__ __forceinline__ bool iou_gt_half(float4 a, float aa, float4 b, float ab) {
  const float xx1 = fmaxf(a.x, b.x);
  const float yy1 = fmaxf(a.y, b.y);
  const float xx2 = fminf(a.z, b.z);
  const float yy2 = fminf(a.w, b.w);
  const float iw  = fmaxf(__fsub_rn(xx2, xx1), 0.0f);
  const float ih  = fmaxf(__fsub_rn(yy2, yy1), 0.0f);
  const float inter = __fmul_rn(iw, ih);
  const float denom = __fsub_rn(__fadd_rn(aa, ab), inter);
  return __fdiv_rn(inter, denom) > 0.5f;
}

__device__ __forceinline__ float rdlanef(float v, int s) {
  return __uint_as_float(__builtin_amdgcn_readlane(__float_as_uint(v), s));
}

// cls [B, N, 80] -> clsT [B, 80, N]; tile = 160 anchors x 80 classes.
__global__ __launch_bounds__(TP_T)
void transpose_kernel(const float* __restrict__ cls, float* __restrict__ clsT)
{
  const int blk  = blockIdx.x;           // b * 125 + tile
  const int b    = blk / 125;
  const int tile = blk - b * 125;
  const int n0   = tile * TILE_A;
  const int t    = threadIdx.x;

  __shared__ float4 lds[N_CLS * 41];     // 52.5 KB

  const float4* in4 =
      reinterpret_cast<const float4*>(cls + ((size_t)b * N_ANCH + n0) * N_CLS);
  float* ldsF = reinterpret_cast<float*>(lds);

#pragma unroll
  for (int i = 0; i < 10; ++i) {
    const int f4 = t + i * TP_T;         // < 3200
    const float4 v = in4[f4];
    const int a  = f4 / 20;              // anchor within tile
    const int c0 = (f4 - a * 20) * 4;    // class of v.x
    ldsF[(c0 + 0) * 164 + a] = v.x;
    ldsF[(c0 + 1) * 164 + a] = v.y;
    ldsF[(c0 + 2) * 164 + a] = v.z;
    ldsF[(c0 + 3) * 164 + a] = v.w;
  }
  __syncthreads();

  float4* out4 = reinterpret_cast<float4*>(clsT + (size_t)b * N_CLS * N_ANCH);
#pragma unroll
  for (int i = 0; i < 10; ++i) {
    const int f4 = t + i * TP_T;         // < 3200
    const int c  = f4 / 40;              // 40 float4 per class row
    const int a4 = f4 - c * 40;
    out4[(size_t)c * (N_ANCH / 4) + (n0 / 4) + a4] = lds[c * 41 + a4];
  }
}

// ---- SELECT: phase1 + histogram select + bitonic sort (round 1) ----
// Outputs: sKeys[bc][1024] sorted desc (zeros at end), sHdr[bc]={cnt,btEff},
// sHisto[bc][1024] suffix-sum histogram (for scan-side fallback rounds).
__global__ __launch_bounds__(NMS_T)
void nms_select_kernel(const float* __restrict__ cls,
                       const float* __restrict__ clsT,
                       unsigned long long* __restrict__ sKeys,
                       uint2* __restrict__ sHdr,
                       unsigned* __restrict__ sHisto, int useT)
{
  const int bc  = blockIdx.x;
  const int b   = bc / N_CLS;
  const int c   = bc - b * N_CLS;
  const int tid = threadIdx.x;

  __shared__ unsigned long long keys[SORTN];   // 8 KB
  __shared__ unsigned histo[NB];               // 4 KB (becomes suffix-sum)
  __shared__ int sh_cnt, sh_bt;

  for (int i = tid; i < NB; i += NMS_T) histo[i] = 0;
  __syncthreads();

  // phase 1: read scores into regs, build histogram
  float sc[ELEMS];
  if (useT) {
    const float4* cT4 =
        reinterpret_cast<const float4*>(clsT + (size_t)bc * N_ANCH);
#pragma unroll
    for (int k = 0; k < 10; ++k) {
      const int f4 = tid + (k << 9);
      float4 v = make_float4(-1.f, -1.f, -1.f, -1.f);
      if (f4 < N_ANCH / 4) v = cT4[f4];
#pragma unroll
      for (int m = 0; m < 4; ++m) {
        const float t = (&v.x)[m];
        const float val = (t > 0.05f) ? t : -1.0f;
        sc[k * 4 + m] = val;
        if (val > 0.0f) {
          int bk = (int)(__float_as_uint(val) >> 16) - BUCKET_BASE;
          if (bk > NB - 1) bk = NB - 1;
          atomicAdd(&histo[bk], 1u);
        }
      }
    }
  } else {
    const float* clsB = cls + ((size_t)b * N_ANCH) * N_CLS + c;
#pragma unroll
    for (int k = 0; k < 10; ++k) {
      const int f4 = tid + (k << 9);
#pragma unroll
      for (int m = 0; m < 4; ++m) {
        const int j = (f4 << 2) + m;
        float val = -1.0f;
        if (j < N_ANCH) {
          const float t = clsB[(size_t)j * N_CLS];
          if (t > 0.05f) val = t;
        }
        sc[k * 4 + m] = val;
        if (val > 0.0f) {
          int bk = (int)(__float_as_uint(val) >> 16) - BUCKET_BASE;
          if (bk > NB - 1) bk = NB - 1;
          atomicAdd(&histo[bk], 1u);
        }
      }
    }
  }
  __syncthreads();

  // suffix sum: histo[i] = #elems in buckets >= i
  for (int d = 1; d < NB; d <<= 1) {
    const int i0 = tid, i1 = tid + NMS_T;
    const unsigned a0 = (i0 + d < NB) ? histo[i0 + d] : 0u;
    const unsigned a1 = (i1 + d < NB) ? histo[i1 + d] : 0u;
    __syncthreads();
    histo[i0] += a0; histo[i1] += a1;
    __syncthreads();
  }

  // round-1 selection (loop only to skip empty ranges)
  int btPrev = NB;
  unsigned processed = 0;
  int cnt = 0, btEff = 0;

  while (true) {
    if (tid == 0) { sh_bt = 0; sh_cnt = 0; }
    __syncthreads();
    for (int i = tid; i < NB; i += NMS_T) {
      if (i < btPrev) {
        const unsigned rem  = histo[i] - processed;
        const unsigned remN = (i + 1 < btPrev) ? (histo[i + 1] - processed) : 0u;
        if (rem >= KSEL && remN < KSEL) sh_bt = i;
      }
    }
    __syncthreads();
    const int bt = sh_bt;

    int lo = bt;
#pragma unroll
    for (int k = 0; k < ELEMS; ++k) {
      const float v = sc[k];
      if (v > 0.0f) {
        int bk = (int)(__float_as_uint(v) >> 16) - BUCKET_BASE;
        if (bk > NB - 1) bk = NB - 1;
        if (bk >= lo && bk < btPrev) {
          const int pos = atomicAdd(&sh_cnt, 1);
          if (pos < SORTN) {
            const int j = ((tid + ((k >> 2) << 9)) << 2) + (k & 3);
            keys[pos] = ((unsigned long long)__float_as_uint(v) << 16)
                      | (unsigned long long)(0xFFFFu - (unsigned)j);
          }
        }
      }
    }
    __syncthreads();
    btEff = bt;
    if (sh_cnt > SORTN && bt + 1 < btPrev) {
      if (tid == 0) sh_cnt = 0;
      __syncthreads();
      lo = bt + 1;
#pragma unroll
      for (int k = 0; k < ELEMS; ++k) {
        const float v = sc[k];
        if (v > 0.0f) {
          int bk = (int)(__float_as_uint(v) >> 16) - BUCKET_BASE;
          if (bk > NB - 1) bk = NB - 1;
          if (bk >= lo && bk < btPrev) {
            const int pos = atomicAdd(&sh_cnt, 1);
            if (pos < SORTN) {
              const int j = ((tid + ((k >> 2) << 9)) << 2) + (k & 3);
              keys[pos] = ((unsigned long long)__float_as_uint(v) << 16)
                        | (unsigned long long)(0xFFFFu - (unsigned)j);
            }
          }
        }
      }
      __syncthreads();
      btEff = bt + 1;
    }
    cnt = sh_cnt < SORTN ? sh_cnt : SORTN;

    if (cnt == 0) {
      if (btEff == 0) break;
      processed = histo[btEff]; btPrev = btEff;
      continue;
    }
    for (int i = cnt + tid; i < SORTN; i += NMS_T) keys[i] = 0ull;
    __syncthreads();

    // bitonic sort 1024 desc (zeros sink)
    for (int kk = 2; kk <= SORTN; kk <<= 1) {
      for (int jj = kk >> 1; jj > 0; jj >>= 1) {
        for (int i = tid; i < SORTN; i += NMS_T) {
          const int l = i ^ jj;
          if (l > i) {
            const unsigned long long a = keys[i], bv = keys[l];
            const bool up = ((i & kk) == 0);
            if (up ? (a < bv) : (a > bv)) { keys[i] = bv; keys[l] = a; }
          }
        }
        __syncthreads();
      }
    }
    break;
  }

  // write outputs
  for (int i = tid; i < SORTN; i += NMS_T)
    sKeys[(size_t)bc * SORTN + i] = (cnt > 0) ? keys[i] : 0ull;
  for (int i = tid; i < NB; i += NMS_T)
    sHisto[(size_t)bc * NB + i] = histo[i];
  if (tid == 0) sHdr[bc] = make_uint2((unsigned)cnt, (unsigned)btEff);
}

// ---- SCAN: greedy NMS over sorted keys; fallback selection if exhausted ----
__global__ __launch_bounds__(NMS_T)
void nms_scan_kernel(const float* __restrict__ boxes,
                     const float* __restrict__ cls,
                     const float* __restrict__ clsT,
                     const unsigned long long* __restrict__ sKeysG,
                     const uint2* __restrict__ sHdr,
                     const unsigned* __restrict__ sHistoG,
                     unsigned long long* __restrict__ pKeys,
                     unsigned* __restrict__ pAnch,
                     unsigned* __restrict__ gHist, int useT)
{
  const int bc  = blockIdx.x;
  const int b   = bc / N_CLS;
  const int c   = bc - b * N_CLS;
  const int tid = threadIdx.x;

  const float4* boxesB = reinterpret_cast<const float4*>(boxes) + (size_t)b * N_ANCH;

  __shared__ unsigned long long keys[SORTN];   // 8 KB
  __shared__ unsigned histo[NB];               // 4 KB (fallback only, then reused)
  __shared__ float4 pBox[MAXDET];
  __shared__ float  pArea[MAXDET];
  __shared__ int    pBk[MAXDET];
  __shared__ int sh_cnt, sh_np, sh_bt;

  const uint2 hdr = sHdr[bc];
  int cnt   = (int)hdr.x;
  int btEff = (int)hdr.y;
  for (int i = tid; i < SORTN; i += NMS_T)
    keys[i] = sKeysG[(size_t)bc * SORTN + i];
  if (tid == 0) sh_np = 0;
  __syncthreads();

  bool histoLoaded = false;
  int btPrev = NB;
  unsigned processed = 0;

  while (true) {
    // ---- batch-64 wave-parallel greedy scan (wave 0) ----
    if (cnt > 0 && tid < 64) {
      const int lane = tid;
      int np = sh_np;
      for (int i0 = 0; i0 < cnt && np < MAXDET; i0 += 64) {
        const int ci = i0 + lane;
        const bool haveC = ci < cnt;
        unsigned long long key = 0ull;
        if (haveC) key = keys[ci];
        const int idx = 0xFFFF - (int)(key & 0xFFFFull);
        // candidate key: sbits in [47:16] -> bucket = (key>>32) - BASE
        int myBk = (int)(key >> 32) - BUCKET_BASE;
        if (myBk > NB - 1) myBk = NB - 1;
        if (myBk < 0) myBk = 0;
        float4 cb = make_float4(0.f, 0.f, 0.f, 0.f);
        if (haveC) cb = boxesB[idx];
        const float ca = box_area(cb);
        bool alive = haveC;
        for (int j = 0; j < np; ++j) {
          if (alive && iou_gt_half(cb, ca, pBox[j], pArea[j])) alive = false;
        }
        unsigned long long remM = __ballot(alive);
        while (remM != 0ull && np < MAXDET) {
          const int s = __ffsll(remM) - 1;     // wave-uniform
          const float bx = rdlanef(cb.x, s), by = rdlanef(cb.y, s);
          const float bz = rdlanef(cb.z, s), bw = rdlanef(cb.w, s);
          const float4 sb = make_float4(bx, by, bz, bw);
          const float ba = box_area(sb);       // bit-identical recompute
          const int   bkp = __builtin_amdgcn_readlane(myBk, s);
          if (lane == s) {
            const unsigned sbits = (unsigned)(key >> 16);
            const unsigned long long pk =
                ((unsigned long long)sbits << 32) |
                (unsigned long long)(0xFFFFFFFFu - (unsigned)(c * MAXDET + np));
            pKeys[(size_t)bc * MAXDET + np] = pk;
            pAnch[(size_t)bc * MAXDET + np] = (unsigned)idx;
            alive = false;
          }
          if (lane == 0) {
            pBox[np] = sb; pArea[np] = ba; pBk[np] = bkp;
          }
          if (alive && lane > s) {
            if (iou_gt_half(cb, ca, sb, ba)) alive = false;
          }
          ++np;
          remM = __ballot(alive);
        }
      }
      if (lane == 0) sh_np = np;
    }
    __syncthreads();
    if (sh_np >= MAXDET || btEff == 0) break;

    // ---- fallback selection round (never expected at these sizes) ----
    if (!histoLoaded) {
      for (int i = tid; i < NB; i += NMS_T)
        histo[i] = sHistoG[(size_t)bc * NB + i];
      histoLoaded = true;
      __syncthreads();
    }
    processed = histo[btEff]; btPrev = btEff;

    if (tid == 0) { sh_bt = 0; sh_cnt = 0; }
    __syncthreads();
    for (int i = tid; i < NB; i += NMS_T) {
      if (i < btPrev) {
        const unsigned rem  = histo[i] - processed;
        const unsigned remN = (i + 1 < btPrev) ? (histo[i + 1] - processed) : 0u;
        if (rem >= KSEL && remN < KSEL) sh_bt = i;
      }
    }
    __syncthreads();
    const int bt = sh_bt;

    for (int pass = 0; pass < 2; ++pass) {
      const int lo = (pass == 0) ? bt : bt + 1;
      for (int j = tid; j < N_ANCH; j += NMS_T) {
        float val = -1.0f;
        if (useT) {
          const float t = clsT[(size_t)bc * N_ANCH + j];
          if (t > 0.05f) val = t;
        } else {
          const float t = cls[((size_t)b * N_ANCH + j) * N_CLS + c];
          if (t > 0.05f) val = t;
        }
        if (val > 0.0f) {
          int bk = (int)(__float_as_uint(val) >> 16) - BUCKET_BASE;
          if (bk > NB - 1) bk = NB - 1;
          if (bk >= lo && bk < btPrev) {
            const int pos = atomicAdd(&sh_cnt, 1);
            if (pos < SORTN) {
              keys[pos] = ((unsigned long long)__float_as_uint(val) << 16)
                        | (unsigned long long)(0xFFFFu - (unsigned)j);
            }
          }
        }
      }
      __syncthreads();
      btEff = lo;
      if (sh_cnt > SORTN && bt + 1 < btPrev && pass == 0) {
        if (tid == 0) sh_cnt = 0;
        __syncthreads();
        continue;  // redo excluding boundary bucket
      }
      break;
    }
    cnt = sh_cnt < SORTN ? sh_cnt : SORTN;

    if (cnt == 0) {
      if (btEff == 0) break;
      continue;  // loop re-enters scan (skipped: cnt==0), then next fallback
    }
    for (int i = cnt + tid; i < SORTN; i += NMS_T) keys[i] = 0ull;
    __syncthreads();
    for (int kk = 2; kk <= SORTN; kk <<= 1) {
      for (int jj = kk >> 1; jj > 0; jj >>= 1) {
        for (int i = tid; i < SORTN; i += NMS_T) {
          const int l = i ^ jj;
          if (l > i) {
            const unsigned long long a = keys[i], bv = keys[l];
            const bool up = ((i & kk) == 0);
            if (up ? (a < bv) : (a > bv)) { keys[i] = bv; keys[l] = a; }
          }
        }
        __syncthreads();
      }
    }
  }
  __syncthreads();

  const int npF = sh_np;
  for (int r = npF + tid; r < MAXDET; r += NMS_T) {
    pKeys[(size_t)bc * MAXDET + r] = 0ull;
    pAnch[(size_t)bc * MAXDET + r] = 0u;
  }
  // pick-bucket histogram -> global per-image (spread atomics)
  for (int i = tid; i < NB; i += NMS_T) histo[i] = 0;
  __syncthreads();
  if (tid < npF) atomicAdd(&histo[pBk[tid]], 1u);
  __syncthreads();
  for (int i = tid; i < NB; i += NMS_T) {
    const unsigned v = histo[i];
    if (v) atomicAdd(&gHist[b * NB + i], v);
  }
}

// One block per image, 1024 threads: exact top-300 of the 24000 pick keys.
__global__ __launch_bounds__(MERGE_T)
void topk_merge_kernel(const unsigned long long* __restrict__ pKeys,
                       const unsigned* __restrict__ pAnch,
                       const unsigned* __restrict__ gHist,
                       const float* __restrict__ boxes,
                       float* __restrict__ out, int B)
{
  const int b   = blockIdx.x;
  const int tid = threadIdx.x;
  const unsigned long long* pk = pKeys + (size_t)b * N_CLS * MAXDET;
  const unsigned* pa = pAnch + (size_t)b * N_CLS * MAXDET;
  const int TOT = N_CLS * MAXDET;

  __shared__ unsigned long long mk[MSORT];
  __shared__ unsigned ma_[MSORT];
  __shared__ unsigned histo[NB];
  __shared__ unsigned histo2[256];
  __shared__ int sh_cnt, sh_b1, sh_b2;

  histo[tid] = gHist[b * NB + tid];
  if (tid < 256) histo2[tid] = 0;
  if (tid == 0) { sh_cnt = 0; sh_b1 = -1; sh_b2 = 0; }
  __syncthreads();

  for (int d = 1; d < NB; d <<= 1) {
    const unsigned a0 = (tid + d < NB) ? histo[tid + d] : 0u;
    __syncthreads();
    histo[tid] += a0;
    __syncthreads();
  }
  const unsigned total = histo[0];

  int b1 = -1, b2 = 0;
  if (total > MAXDET) {
    {
      const unsigned rem  = histo[tid];
      const unsigned remN = (tid + 1 < NB) ? histo[tid + 1] : 0u;
      if (rem >= MAXDET && remN < MAXDET) sh_b1 = tid;
    }
    __syncthreads();
    b1 = sh_b1;
    const unsigned above = (b1 + 1 < NB) ? histo[b1 + 1] : 0u;
    const unsigned need2 = MAXDET - above;
    for (int i = tid; i < TOT; i += MERGE_T) {
      const unsigned long long key = pk[i];
      if (key != 0ull) {
        int bk = (int)(key >> 48) - BUCKET_BASE;   // pick key: sbits in [63:32]
        if (bk > NB - 1) bk = NB - 1;
        if (bk < 0) bk = 0;
        if (bk == b1) atomicAdd(&histo2[(unsigned)(key >> 40) & 0xFFu], 1u);
      }
    }
    __syncthreads();
    for (int d = 1; d < 256; d <<= 1) {
      unsigned a0 = 0;
      if (tid < 256) a0 = (tid + d < 256) ? histo2[tid + d] : 0u;
      __syncthreads();
      if (tid < 256) histo2[tid] += a0;
      __syncthreads();
    }
    if (tid < 256) {
      const unsigned rem  = histo2[tid];
      const unsigned remN = (tid + 1 < 256) ? histo2[tid + 1] : 0u;
      if (rem >= need2 && remN < need2) sh_b2 = tid;
    }
    __syncthreads();
    b2 = sh_b2;
  }

  mk[tid] = 0ull;
  __syncthreads();
  for (int i = tid; i < TOT; i += MERGE_T) {
    const unsigned long long key = pk[i];
    if (key != 0ull) {
      int k1 = (int)(key >> 48) - BUCKET_BASE;
      if (k1 > NB - 1) k1 = NB - 1;
      if (k1 < 0) k1 = 0;
      const int k2 = (int)((key >> 40) & 0xFFull);
      if (k1 > b1 || (k1 == b1 && k2 >= b2)) {
        const int pos = atomicAdd(&sh_cnt, 1);
        if (pos < MSORT) { mk[pos] = key; ma_[pos] = pa[i]; }
      }
    }
  }
  __syncthreads();

  for (int kk = 2; kk <= MSORT; kk <<= 1) {
    for (int jj = kk >> 1; jj > 0; jj >>= 1) {
      const int i = tid;
      const int l = i ^ jj;
      if (l > i) {
        const unsigned long long a = mk[i], bv = mk[l];
        const bool up = ((i & kk) == 0);
        if (up ? (a < bv) : (a > bv)) {
          mk[i] = bv; mk[l] = a;
          const unsigned t = ma_[i]; ma_[i] = ma_[l]; ma_[l] = t;
        }
      }
      __syncthreads();
    }
  }

  float* outBoxes  = out;                            // [B,300,4]
  float* outScores = out + (size_t)B * MAXDET * 4;   // [B,300]
  float* outLabels = out + (size_t)B * MAXDET * 5;   // [B,300] (as float)
  if (tid < MAXDET) {
    const unsigned long long key = mk[tid];
    const size_t o = (size_t)b * MAXDET + tid;
    if (key == 0ull) {
      reinterpret_cast<float4*>(outBoxes)[o] = make_float4(-1.f, -1.f, -1.f, -1.f);
      outScores[o] = -1.f;
      outLabels[o] = -1.f;
    } else {
      const unsigned posFlat = 0xFFFFFFFFu - (unsigned)(key & 0xFFFFFFFFull);
      const int ccls = (int)(posFlat / MAXDET);
      reinterpret_cast<float4*>(outBoxes)[o] =
          reinterpret_cast<const float4*>(boxes)[(size_t)b * N_ANCH + ma_[tid]];
      outScores[o] = __uint_as_float((unsigned)(key >> 32));
      outLabels[o] = (float)ccls;
    }
  }
}

extern "C" void kernel_launch(void* const* d_in, const int* in_sizes, int n_in,
                              void* d_out, int out_size, void* d_ws, size_t ws_size,
                              hipStream_t stream)
{
  const float* boxes = (const float*)d_in[0];
  const float* cls   = (const float*)d_in[1];
  const int B = in_sizes[0] / (N_ANCH * 4);  // = 2
  const int NBC = B * N_CLS;

  // ws layout (8B-aligned first): sKeys u64 | pKeys u64 | sHdr uint2 |
  //   sHisto u32 | pAnch u32 | gHist u32 | clsT f32 (optional)
  const size_t sKeysBytes = (size_t)NBC * SORTN * sizeof(unsigned long long);
  const size_t pKeysBytes = (size_t)NBC * MAXDET * sizeof(unsigned long long);
  const size_t sHdrBytes  = (size_t)NBC * sizeof(uint2);
  const size_t sHistBytes = (size_t)NBC * NB * sizeof(unsigned);
  const size_t pAnchBytes = (size_t)NBC * MAXDET * sizeof(unsigned);
  const size_t gHistBytes = (size_t)B * NB * sizeof(unsigned);
  const size_t clsTBytes  = (size_t)B * N_CLS * N_ANCH * sizeof(float);

  char* p = (char*)d_ws;
  unsigned long long* sKeys = (unsigned long long*)p;  p += sKeysBytes;
  unsigned long long* pKeys = (unsigned long long*)p;  p += pKeysBytes;
  uint2*    sHdr  = (uint2*)p;                         p += sHdrBytes;
  unsigned* sHist = (unsigned*)p;                      p += sHistBytes;
  unsigned* pAnch = (unsigned*)p;                      p += pAnchBytes;
  unsigned* gHist = (unsigned*)p;                      p += gHistBytes;
  float*    clsT  = (float*)p;                         p += clsTBytes;
  const int useT = (ws_size >= (size_t)(p - (char*)d_ws)) ? 1 : 0;

  hipMemsetAsync(gHist, 0, gHistBytes, stream);
  if (useT) {
    transpose_kernel<<<dim3(B * (N_ANCH / TILE_A)), dim3(TP_T), 0, stream>>>(cls, clsT);
  }
  nms_select_kernel<<<dim3(NBC), dim3(NMS_T), 0, stream>>>(
      cls, clsT, sKeys, sHdr, sHist, useT);
  nms_scan_kernel<<<dim3(NBC), dim3(NMS_T), 0, stream>>>(
      boxes, cls, clsT, sKeys, sHdr, sHist, pKeys, pAnch, gHist, useT);
  topk_merge_kernel<<<dim3(B), dim3(MERGE_T), 0, stream>>>(
      pKeys, pAnch, gHist, boxes, (float*)d_out, B);
}

// Round 12
// 187.154 us; speedup vs baseline: 3.1337x; 1.5682x over previous
//
#include <hip/hip_runtime.h>
#include <cstdint>
#include <cstddef>

#define N_ANCH 20000
#define N_CLS  80
#define MAXDET 300
#define NMS_T  512
#define ELEMS  40      // scores per thread in select (10 float4)
#define SORTN  1024    // bitonic sort size (pow2)
#define KSEL   768     // target top-K per selection round
#define NB     1024    // coarse histogram buckets (564 used; pow2)
#define MSORT  1024    // merge sort size
#define MERGE_T 1024   // merge threads
#define BUCKET_BASE 0x3D4C  // float bits of ~0.05 >> 16

#define TP_T   320     // transpose threads
#define TILE_A 160     // anchors per transpose tile (20000 = 125 * 160)

__device__ __forceinline__ float box_area(float4 b) {
  return __fmul_rn(__fsub_rn(b.z, b.x), __fsub_rn(b.w, b.y));
}

// IOU, unfused IEEE ops, exactly the reference's association order.
// a = candidate (its area first in denom), b = picked/earlier.
__device__ __forceinline__ bool iou_gt_half(float4 a, float aa, float4 b, float ab) {
  const float xx1 = fmaxf(a.x, b.x);
  const float yy1 = fmaxf(a.y, b.y);
  const float xx2 = fminf(a.z, b.z);
  const float yy2 = fminf(a.w, b.w);
  const float iw  = fmaxf(__fsub_rn(xx2, xx1), 0.0f);
  const float ih  = fmaxf(__fsub_rn(yy2, yy1), 0.0f);
  const float inter = __fmul_rn(iw, ih);
  const float denom = __fsub_rn(__fadd_rn(aa, ab), inter);
  return __fdiv_rn(inter, denom) > 0.5f;
}

__device__ __forceinline__ float rdlanef(float v, int s) {
  return __uint_as_float(__builtin_amdgcn_readlane(__float_as_uint(v), s));
}

// cls [B, N, 80] -> clsT [B, 80, N]; tile = 160 anchors x 80 classes.
__global__ __launch_bounds__(TP_T)
void transpose_kernel(const float* __restrict__ cls, float* __restrict__ clsT)
{
  const int blk  = blockIdx.x;           // b * 125 + tile
  const int b    = blk / 125;
  const int tile = blk - b * 125;
  const int n0   = tile * TILE_A;
  const int t    = threadIdx.x;

  __shared__ float4 lds[N_CLS * 41];     // 52.5 KB

  const float4* in4 =
      reinterpret_cast<const float4*>(cls + ((size_t)b * N_ANCH + n0) * N_CLS);
  float* ldsF = reinterpret_cast<float*>(lds);

#pragma unroll
  for (int i = 0; i < 10; ++i) {
    const int f4 = t + i * TP_T;         // < 3200
    const float4 v = in4[f4];
    const int a  = f4 / 20;              // anchor within tile
    const int c0 = (f4 - a * 20) * 4;    // class of v.x
    ldsF[(c0 + 0) * 164 + a] = v.x;
    ldsF[(c0 + 1) * 164 + a] = v.y;
    ldsF[(c0 + 2) * 164 + a] = v.z;
    ldsF[(c0 + 3) * 164 + a] = v.w;
  }
  __syncthreads();

  float4* out4 = reinterpret_cast<float4*>(clsT + (size_t)b * N_CLS * N_ANCH);
#pragma unroll
  for (int i = 0; i < 10; ++i) {
    const int f4 = t + i * TP_T;         // < 3200
    const int c  = f4 / 40;              // 40 float4 per class row
    const int a4 = f4 - c * 40;
    out4[(size_t)c * (N_ANCH / 4) + (n0 / 4) + a4] = lds[c * 41 + a4];
  }
}

// ---- SELECT: phase1 + histogram select + bitonic sort (round 1) ----
__global__ __launch_bounds__(NMS_T)
void nms_select_kernel(const float* __restrict__ cls,
                       const float* __restrict__ clsT,
                       unsigned long long* __restrict__ sKeys,
                       uint2* __restrict__ sHdr,
                       unsigned* __restrict__ sHisto, int useT)
{
  const int bc  = blockIdx.x;
  const int b   = bc / N_CLS;
  const int c   = bc - b * N_CLS;
  const int tid = threadIdx.x;

  __shared__ unsigned long long keys[SORTN];   // 8 KB
  __shared__ unsigned histo[NB];               // 4 KB (becomes suffix-sum)
  __shared__ int sh_cnt, sh_bt;

  for (int i = tid; i < NB; i += NMS_T) histo[i] = 0;
  __syncthreads();

  float sc[ELEMS];
  if (useT) {
    const float4* cT4 =
        reinterpret_cast<const float4*>(clsT + (size_t)bc * N_ANCH);
#pragma unroll
    for (int k = 0; k < 10; ++k) {
      const int f4 = tid + (k << 9);
      float4 v = make_float4(-1.f, -1.f, -1.f, -1.f);
      if (f4 < N_ANCH / 4) v = cT4[f4];
#pragma unroll
      for (int m = 0; m < 4; ++m) {
        const float t = (&v.x)[m];
        const float val = (t > 0.05f) ? t : -1.0f;
        sc[k * 4 + m] = val;
        if (val > 0.0f) {
          int bk = (int)(__float_as_uint(val) >> 16) - BUCKET_BASE;
          if (bk > NB - 1) bk = NB - 1;
          atomicAdd(&histo[bk], 1u);
        }
      }
    }
  } else {
    const float* clsB = cls + ((size_t)b * N_ANCH) * N_CLS + c;
#pragma unroll
    for (int k = 0; k < 10; ++k) {
      const int f4 = tid + (k << 9);
#pragma unroll
      for (int m = 0; m < 4; ++m) {
        const int j = (f4 << 2) + m;
        float val = -1.0f;
        if (j < N_ANCH) {
          const float t = clsB[(size_t)j * N_CLS];
          if (t > 0.05f) val = t;
        }
        sc[k * 4 + m] = val;
        if (val > 0.0f) {
          int bk = (int)(__float_as_uint(val) >> 16) - BUCKET_BASE;
          if (bk > NB - 1) bk = NB - 1;
          atomicAdd(&histo[bk], 1u);
        }
      }
    }
  }
  __syncthreads();

  for (int d = 1; d < NB; d <<= 1) {
    const int i0 = tid, i1 = tid + NMS_T;
    const unsigned a0 = (i0 + d < NB) ? histo[i0 + d] : 0u;
    const unsigned a1 = (i1 + d < NB) ? histo[i1 + d] : 0u;
    __syncthreads();
    histo[i0] += a0; histo[i1] += a1;
    __syncthreads();
  }

  int btPrev = NB;
  unsigned processed = 0;
  int cnt = 0, btEff = 0;

  while (true) {
    if (tid == 0) { sh_bt = 0; sh_cnt = 0; }
    __syncthreads();
    for (int i = tid; i < NB; i += NMS_T) {
      if (i < btPrev) {
        const unsigned rem  = histo[i] - processed;
        const unsigned remN = (i + 1 < btPrev) ? (histo[i + 1] - processed) : 0u;
        if (rem >= KSEL && remN < KSEL) sh_bt = i;
      }
    }
    __syncthreads();
    const int bt = sh_bt;

    int lo = bt;
#pragma unroll
    for (int k = 0; k < ELEMS; ++k) {
      const float v = sc[k];
      if (v > 0.0f) {
        int bk = (int)(__float_as_uint(v) >> 16) - BUCKET_BASE;
        if (bk > NB - 1) bk = NB - 1;
        if (bk >= lo && bk < btPrev) {
          const int pos = atomicAdd(&sh_cnt, 1);
          if (pos < SORTN) {
            const int j = ((tid + ((k >> 2) << 9)) << 2) + (k & 3);
            keys[pos] = ((unsigned long long)__float_as_uint(v) << 16)
                      | (unsigned long long)(0xFFFFu - (unsigned)j);
          }
        }
      }
    }
    __syncthreads();
    btEff = bt;
    if (sh_cnt > SORTN && bt + 1 < btPrev) {
      if (tid == 0) sh_cnt = 0;
      __syncthreads();
      lo = bt + 1;
#pragma unroll
      for (int k = 0; k < ELEMS; ++k) {
        const float v = sc[k];
        if (v > 0.0f) {
          int bk = (int)(__float_as_uint(v) >> 16) - BUCKET_BASE;
          if (bk > NB - 1) bk = NB - 1;
          if (bk >= lo && bk < btPrev) {
            const int pos = atomicAdd(&sh_cnt, 1);
            if (pos < SORTN) {
              const int j = ((tid + ((k >> 2) << 9)) << 2) + (k & 3);
              keys[pos] = ((unsigned long long)__float_as_uint(v) << 16)
                        | (unsigned long long)(0xFFFFu - (unsigned)j);
            }
          }
        }
      }
      __syncthreads();
      btEff = bt + 1;
    }
    cnt = sh_cnt < SORTN ? sh_cnt : SORTN;

    if (cnt == 0) {
      if (btEff == 0) break;
      processed = histo[btEff]; btPrev = btEff;
      continue;
    }
    for (int i = cnt + tid; i < SORTN; i += NMS_T) keys[i] = 0ull;
    __syncthreads();

    for (int kk = 2; kk <= SORTN; kk <<= 1) {
      for (int jj = kk >> 1; jj > 0; jj >>= 1) {
        for (int i = tid; i < SORTN; i += NMS_T) {
          const int l = i ^ jj;
          if (l > i) {
            const unsigned long long a = keys[i], bv = keys[l];
            const bool up = ((i & kk) == 0);
            if (up ? (a < bv) : (a > bv)) { keys[i] = bv; keys[l] = a; }
          }
        }
        __syncthreads();
      }
    }
    break;
  }

  for (int i = tid; i < SORTN; i += NMS_T)
    sKeys[(size_t)bc * SORTN + i] = (cnt > 0) ? keys[i] : 0ull;
  for (int i = tid; i < NB; i += NMS_T)
    sHisto[(size_t)bc * NB + i] = histo[i];
  if (tid == 0) sHdr[bc] = make_uint2((unsigned)cnt, (unsigned)btEff);
}

// ---- SCAN: batch-parallel greedy NMS with bitmask resolution (exact) ----
__global__ __launch_bounds__(NMS_T)
void nms_scan_kernel(const float* __restrict__ boxes,
                     const float* __restrict__ cls,
                     const float* __restrict__ clsT,
                     const unsigned long long* __restrict__ sKeysG,
                     const uint2* __restrict__ sHdr,
                     const unsigned* __restrict__ sHistoG,
                     unsigned long long* __restrict__ pKeys,
                     unsigned* __restrict__ pAnch,
                     unsigned* __restrict__ gHist, int useT)
{
  const int bc   = blockIdx.x;
  const int b    = bc / N_CLS;
  const int c    = bc - b * N_CLS;
  const int tid  = threadIdx.x;
  const int lane = tid & 63;
  const int wv   = tid >> 6;                    // 8 waves

  const float4* boxesB = reinterpret_cast<const float4*>(boxes) + (size_t)b * N_ANCH;

  __shared__ unsigned long long keys[SORTN];    // 8 KB
  __shared__ unsigned histo[NB];                // 4 KB (fallback; reused at end)
  __shared__ float4 pBox[MAXDET];
  __shared__ float  pArea[MAXDET];
  __shared__ int    pBk[MAXDET];
  __shared__ unsigned long long lmask[8][64];   // 4 KB pairwise conflict masks
  __shared__ unsigned long long smask[8];       // prior-pick suppression ballots
  __shared__ int sh_cnt, sh_np, sh_bt;

  const uint2 hdr = sHdr[bc];
  int cnt   = (int)hdr.x;
  int btEff = (int)hdr.y;
  for (int i = tid; i < SORTN; i += NMS_T)
    keys[i] = sKeysG[(size_t)bc * SORTN + i];
  if (tid == 0) sh_np = 0;
  __syncthreads();

  bool histoLoaded = false;
  int btPrev = NB;
  unsigned processed = 0;

  while (true) {
    // ===== batch-parallel greedy scan (all 8 waves cooperate) =====
    for (int i0 = 0; ; i0 += 64) {
      const int np0 = sh_np;                    // valid: barrier before read
      if (i0 >= cnt || np0 >= MAXDET) break;

      const int ci = i0 + lane;
      const bool haveC = ci < cnt;
      unsigned long long key = 0ull;
      if (haveC) key = keys[ci];
      const int idx = 0xFFFF - (int)(key & 0xFFFFull);
      int myBk = (int)(key >> 32) - BUCKET_BASE;   // candidate key: sbits [47:16]
      if (myBk > NB - 1) myBk = NB - 1;
      if (myBk < 0) myBk = 0;
      float4 cb = make_float4(0.f, 0.f, 0.f, 0.f);
      if (haveC) cb = boxesB[idx];
      const float ca = box_area(cb);

      // (1) prior-pick suppression, pick-strided across waves
      bool sup = false;
      if (haveC) {
        for (int j = wv; j < np0; j += 8) {
          if (iou_gt_half(cb, ca, pBox[j], pArea[j])) { sup = true; break; }
        }
      }
      const unsigned long long sb = __ballot(sup);
      if (lane == 0) smask[wv] = sb;

      // (2) in-batch pairwise conflicts, source-lane-strided across waves
      unsigned long long m = 0ull;
      for (int t = wv; t < 63; t += 8) {
        const float bx = rdlanef(cb.x, t), by = rdlanef(cb.y, t);
        const float bz = rdlanef(cb.z, t), bw = rdlanef(cb.w, t);
        const float ba = rdlanef(ca, t);
        if (haveC && t < lane) {
          if (iou_gt_half(cb, ca, make_float4(bx, by, bz, bw), ba))
            m |= (1ull << t);
        }
      }
      lmask[wv][lane] = m;
      __syncthreads();                          // masks ready

      // (3) merge + scalar greedy resolution + (4) parallel writes (wave 0)
      if (tid < 64) {
        unsigned long long supAll = smask[0];
        unsigned long long cm = lmask[0][lane];
#pragma unroll
        for (int w = 1; w < 8; ++w) {
          supAll |= smask[w];
          cm     |= lmask[w][lane];
        }
        const bool alive = haveC && !((supAll >> lane) & 1ull);
        const unsigned long long aliveM = __ballot(alive);

        unsigned long long accept = 0ull;
        int npl = np0;
        for (int i = 0; i < 64; ++i) {
          if (npl >= MAXDET) break;
          if (!((aliveM >> i) & 1ull)) continue;
          const unsigned mlo =
              __builtin_amdgcn_readlane((unsigned)(cm & 0xFFFFFFFFull), i);
          const unsigned mhi =
              __builtin_amdgcn_readlane((unsigned)(cm >> 32), i);
          const unsigned long long cmi = ((unsigned long long)mhi << 32) | mlo;
          if ((cmi & accept) == 0ull) { accept |= (1ull << i); ++npl; }
        }

        if (alive && ((accept >> lane) & 1ull)) {
          const int rank = __popcll(accept & ((1ull << lane) - 1ull));
          const int slot = np0 + rank;
          const unsigned sbits = (unsigned)(key >> 16);
          const unsigned long long pk =
              ((unsigned long long)sbits << 32) |
              (unsigned long long)(0xFFFFFFFFu - (unsigned)(c * MAXDET + slot));
          pKeys[(size_t)bc * MAXDET + slot] = pk;
          pAnch[(size_t)bc * MAXDET + slot] = (unsigned)idx;
          pBox[slot] = cb; pArea[slot] = ca; pBk[slot] = myBk;
        }
        if (lane == 0) sh_np = npl;
      }
      __syncthreads();                          // state ready for next batch
    }
    if (sh_np >= MAXDET || btEff == 0) break;

    // ---- fallback selection round (never expected at these sizes) ----
    if (!histoLoaded) {
      for (int i = tid; i < NB; i += NMS_T)
        histo[i] = sHistoG[(size_t)bc * NB + i];
      histoLoaded = true;
      __syncthreads();
    }
    processed = histo[btEff]; btPrev = btEff;

    if (tid == 0) { sh_bt = 0; sh_cnt = 0; }
    __syncthreads();
    for (int i = tid; i < NB; i += NMS_T) {
      if (i < btPrev) {
        const unsigned rem  = histo[i] - processed;
        const unsigned remN = (i + 1 < btPrev) ? (histo[i + 1] - processed) : 0u;
        if (rem >= KSEL && remN < KSEL) sh_bt = i;
      }
    }
    __syncthreads();
    const int bt = sh_bt;

    for (int pass = 0; pass < 2; ++pass) {
      const int lo = (pass == 0) ? bt : bt + 1;
      for (int j = tid; j < N_ANCH; j += NMS_T) {
        float val = -1.0f;
        if (useT) {
          const float t = clsT[(size_t)bc * N_ANCH + j];
          if (t > 0.05f) val = t;
        } else {
          const float t = cls[((size_t)b * N_ANCH + j) * N_CLS + c];
          if (t > 0.05f) val = t;
        }
        if (val > 0.0f) {
          int bk = (int)(__float_as_uint(val) >> 16) - BUCKET_BASE;
          if (bk > NB - 1) bk = NB - 1;
          if (bk >= lo && bk < btPrev) {
            const int pos = atomicAdd(&sh_cnt, 1);
            if (pos < SORTN) {
              keys[pos] = ((unsigned long long)__float_as_uint(val) << 16)
                        | (unsigned long long)(0xFFFFu - (unsigned)j);
            }
          }
        }
      }
      __syncthreads();
      btEff = lo;
      if (sh_cnt > SORTN && bt + 1 < btPrev && pass == 0) {
        if (tid == 0) sh_cnt = 0;
        __syncthreads();
        continue;
      }
      break;
    }
    cnt = sh_cnt < SORTN ? sh_cnt : SORTN;

    if (cnt == 0) {
      if (btEff == 0) break;
      continue;
    }
    for (int i = cnt + tid; i < SORTN; i += NMS_T) keys[i] = 0ull;
    __syncthreads();
    for (int kk = 2; kk <= SORTN; kk <<= 1) {
      for (int jj = kk >> 1; jj > 0; jj >>= 1) {
        for (int i = tid; i < SORTN; i += NMS_T) {
          const int l = i ^ jj;
          if (l > i) {
            const unsigned long long a = keys[i], bv = keys[l];
            const bool up = ((i & kk) == 0);
            if (up ? (a < bv) : (a > bv)) { keys[i] = bv; keys[l] = a; }
          }
        }
        __syncthreads();
      }
    }
  }
  __syncthreads();

  const int npF = sh_np;
  for (int r = npF + tid; r < MAXDET; r += NMS_T) {
    pKeys[(size_t)bc * MAXDET + r] = 0ull;
    pAnch[(size_t)bc * MAXDET + r] = 0u;
  }
  // pick-bucket histogram -> global per-image (spread atomics)
  for (int i = tid; i < NB; i += NMS_T) histo[i] = 0;
  __syncthreads();
  if (tid < npF) atomicAdd(&histo[pBk[tid]], 1u);
  __syncthreads();
  for (int i = tid; i < NB; i += NMS_T) {
    const unsigned v = histo[i];
    if (v) atomicAdd(&gHist[b * NB + i], v);
  }
}

// One block per image, 1024 threads: exact top-300 of the 24000 pick keys.
__global__ __launch_bounds__(MERGE_T)
void topk_merge_kernel(const unsigned long long* __restrict__ pKeys,
                       const unsigned* __restrict__ pAnch,
                       const unsigned* __restrict__ gHist,
                       const float* __restrict__ boxes,
                       float* __restrict__ out, int B)
{
  const int b   = blockIdx.x;
  const int tid = threadIdx.x;
  const unsigned long long* pk = pKeys + (size_t)b * N_CLS * MAXDET;
  const unsigned* pa = pAnch + (size_t)b * N_CLS * MAXDET;
  const int TOT = N_CLS * MAXDET;

  __shared__ unsigned long long mk[MSORT];
  __shared__ unsigned ma_[MSORT];
  __shared__ unsigned histo[NB];
  __shared__ unsigned histo2[256];
  __shared__ int sh_cnt, sh_b1, sh_b2;

  histo[tid] = gHist[b * NB + tid];
  if (tid < 256) histo2[tid] = 0;
  if (tid == 0) { sh_cnt = 0; sh_b1 = -1; sh_b2 = 0; }
  __syncthreads();

  for (int d = 1; d < NB; d <<= 1) {
    const unsigned a0 = (tid + d < NB) ? histo[tid + d] : 0u;
    __syncthreads();
    histo[tid] += a0;
    __syncthreads();
  }
  const unsigned total = histo[0];

  int b1 = -1, b2 = 0;
  if (total > MAXDET) {
    {
      const unsigned rem  = histo[tid];
      const unsigned remN = (tid + 1 < NB) ? histo[tid + 1] : 0u;
      if (rem >= MAXDET && remN < MAXDET) sh_b1 = tid;
    }
    __syncthreads();
    b1 = sh_b1;
    const unsigned above = (b1 + 1 < NB) ? histo[b1 + 1] : 0u;
    const unsigned need2 = MAXDET - above;
    for (int i = tid; i < TOT; i += MERGE_T) {
      const unsigned long long key = pk[i];
      if (key != 0ull) {
        int bk = (int)(key >> 48) - BUCKET_BASE;   // pick key: sbits in [63:32]
        if (bk > NB - 1) bk = NB - 1;
        if (bk < 0) bk = 0;
        if (bk == b1) atomicAdd(&histo2[(unsigned)(key >> 40) & 0xFFu], 1u);
      }
    }
    __syncthreads();
    for (int d = 1; d < 256; d <<= 1) {
      unsigned a0 = 0;
      if (tid < 256) a0 = (tid + d < 256) ? histo2[tid + d] : 0u;
      __syncthreads();
      if (tid < 256) histo2[tid] += a0;
      __syncthreads();
    }
    if (tid < 256) {
      const unsigned rem  = histo2[tid];
      const unsigned remN = (tid + 1 < 256) ? histo2[tid + 1] : 0u;
      if (rem >= need2 && remN < need2) sh_b2 = tid;
    }
    __syncthreads();
    b2 = sh_b2;
  }

  mk[tid] = 0ull;
  __syncthreads();
  for (int i = tid; i < TOT; i += MERGE_T) {
    const unsigned long long key = pk[i];
    if (key != 0ull) {
      int k1 = (int)(key >> 48) - BUCKET_BASE;
      if (k1 > NB - 1) k1 = NB - 1;
      if (k1 < 0) k1 = 0;
      const int k2 = (int)((key >> 40) & 0xFFull);
      if (k1 > b1 || (k1 == b1 && k2 >= b2)) {
        const int pos = atomicAdd(&sh_cnt, 1);
        if (pos < MSORT) { mk[pos] = key; ma_[pos] = pa[i]; }
      }
    }
  }
  __syncthreads();

  for (int kk = 2; kk <= MSORT; kk <<= 1) {
    for (int jj = kk >> 1; jj > 0; jj >>= 1) {
      const int i = tid;
      const int l = i ^ jj;
      if (l > i) {
        const unsigned long long a = mk[i], bv = mk[l];
        const bool up = ((i & kk) == 0);
        if (up ? (a < bv) : (a > bv)) {
          mk[i] = bv; mk[l] = a;
          const unsigned t = ma_[i]; ma_[i] = ma_[l]; ma_[l] = t;
        }
      }
      __syncthreads();
    }
  }

  float* outBoxes  = out;                            // [B,300,4]
  float* outScores = out + (size_t)B * MAXDET * 4;   // [B,300]
  float* outLabels = out + (size_t)B * MAXDET * 5;   // [B,300] (as float)
  if (tid < MAXDET) {
    const unsigned long long key = mk[tid];
    const size_t o = (size_t)b * MAXDET + tid;
    if (key == 0ull) {
      reinterpret_cast<float4*>(outBoxes)[o] = make_float4(-1.f, -1.f, -1.f, -1.f);
      outScores[o] = -1.f;
      outLabels[o] = -1.f;
    } else {
      const unsigned posFlat = 0xFFFFFFFFu - (unsigned)(key & 0xFFFFFFFFull);
      const int ccls = (int)(posFlat / MAXDET);
      reinterpret_cast<float4*>(outBoxes)[o] =
          reinterpret_cast<const float4*>(boxes)[(size_t)b * N_ANCH + ma_[tid]];
      outScores[o] = __uint_as_float((unsigned)(key >> 32));
      outLabels[o] = (float)ccls;
    }
  }
}

extern "C" void kernel_launch(void* const* d_in, const int* in_sizes, int n_in,
                              void* d_out, int out_size, void* d_ws, size_t ws_size,
                              hipStream_t stream)
{
  const float* boxes = (const float*)d_in[0];
  const float* cls   = (const float*)d_in[1];
  const int B = in_sizes[0] / (N_ANCH * 4);  // = 2
  const int NBC = B * N_CLS;

  // ws layout (8B-aligned first): sKeys u64 | pKeys u64 | sHdr uint2 |
  //   sHisto u32 | pAnch u32 | gHist u32 | clsT f32 (optional)
  const size_t sKeysBytes = (size_t)NBC * SORTN * sizeof(unsigned long long);
  const size_t pKeysBytes = (size_t)NBC * MAXDET * sizeof(unsigned long long);
  const size_t sHdrBytes  = (size_t)NBC * sizeof(uint2);
  const size_t sHistBytes = (size_t)NBC * NB * sizeof(unsigned);
  const size_t pAnchBytes = (size_t)NBC * MAXDET * sizeof(unsigned);
  const size_t gHistBytes = (size_t)B * NB * sizeof(unsigned);
  const size_t clsTBytes  = (size_t)B * N_CLS * N_ANCH * sizeof(float);

  char* p = (char*)d_ws;
  unsigned long long* sKeys = (unsigned long long*)p;  p += sKeysBytes;
  unsigned long long* pKeys = (unsigned long long*)p;  p += pKeysBytes;
  uint2*    sHdr  = (uint2*)p;                         p += sHdrBytes;
  unsigned* sHist = (unsigned*)p;                      p += sHistBytes;
  unsigned* pAnch = (unsigned*)p;                      p += pAnchBytes;
  unsigned* gHist = (unsigned*)p;                      p += gHistBytes;
  float*    clsT  = (float*)p;                         p += clsTBytes;
  const int useT = (ws_size >= (size_t)(p - (char*)d_ws)) ? 1 : 0;

  hipMemsetAsync(gHist, 0, gHistBytes, stream);
  if (useT) {
    transpose_kernel<<<dim3(B * (N_ANCH / TILE_A)), dim3(TP_T), 0, stream>>>(cls, clsT);
  }
  nms_select_kernel<<<dim3(NBC), dim3(NMS_T), 0, stream>>>(
      cls, clsT, sKeys, sHdr, sHist, useT);
  nms_scan_kernel<<<dim3(NBC), dim3(NMS_T), 0, stream>>>(
      boxes, cls, clsT, sKeys, sHdr, sHist, pKeys, pAnch, gHist, useT);
  topk_merge_kernel<<<dim3(B), dim3(MERGE_T), 0, stream>>>(
      pKeys, pAnch, gHist, boxes, (float*)d_out, B);
}